// Round 20
// baseline (1549.792 us; speedup 1.0000x reference)
//
#include <hip/hip_runtime.h>
#include <cstdint>
#include <cstddef>

// RWKV-7 Tmix forward, MI355X gfx950 — ROUND 24: 3 blocks/CU GEMM + scan v10.
// r23: 704 µs; G1 217 (36.6% = 2-barrier ceiling at 2 blocks/CU). Levers:
// (1) gemm LDS 53248B x3 = 159744 <= 160KB and VGPR 128 supports 16 waves/CU,
// but launch_bounds(256,2) capped residency — raise to (256,3): 3rd co-resident
// block = cross-block TLP that hides the per-kstep staging drain. (2) scan v10:
// 8 time-segments x 2 v-halves (same 1024-block shape, 512 thr, 8 waves share
// staging): critical path 352 -> 224 steps; 22.5 KB LDS, 4 blocks/CU, 32
// waves/CU. Warmup 0.6065^96 unchanged. Everything else as r23.

#define DI __device__ __forceinline__
static constexpr int T_ = 1024, C_ = 2048, H_ = 32;

typedef __attribute__((ext_vector_type(8))) __bf16 bf16x8;
typedef __attribute__((ext_vector_type(4))) float f32x4;
typedef __attribute__((ext_vector_type(8))) unsigned short us8v;
typedef __attribute__((ext_vector_type(4))) unsigned short us4v;
typedef __attribute__((ext_vector_type(2))) unsigned short us2v;

DI float sig_(float z) { return 1.0f / (1.0f + expf(-z)); }

DI unsigned short f2bf(float f) {           // round-to-nearest-even f32 -> bf16
  union { float f; uint32_t u; } v; v.f = f;
  uint32_t u = v.u;
  return (unsigned short)((u + 0x7FFFu + ((u >> 16) & 1u)) >> 16);
}
DI float bf2f(unsigned short h) {
  union { uint32_t u; float f; } v; v.u = ((uint32_t)h) << 16;
  return v.f;
}

// DPP butterfly adds over 16 k-lanes (kq = lane&15).
DI float dpp_xor1_add(float x) {
  int r = __builtin_amdgcn_update_dpp(0, __float_as_int(x), 0xB1, 0xF, 0xF, true);
  return x + __int_as_float(r);
}
DI float dpp_xor2_add(float x) {
  int r = __builtin_amdgcn_update_dpp(0, __float_as_int(x), 0x4E, 0xF, 0xF, true);
  return x + __int_as_float(r);
}
DI float dpp_hm_add(float x) {
  int r = __builtin_amdgcn_update_dpp(0, __float_as_int(x), 0x141, 0xF, 0xF, true);
  return x + __int_as_float(r);
}
DI float dpp_mir_add(float x) {
  int r = __builtin_amdgcn_update_dpp(0, __float_as_int(x), 0x140, 0xF, 0xF, true);
  return x + __int_as_float(r);
}

// async global -> LDS DMA (dest = wave-uniform base + lane*size).
DI void gload16(const float* g, float* l) {
  __builtin_amdgcn_global_load_lds(
      (const __attribute__((address_space(1))) uint32_t*)g,
      (__attribute__((address_space(3))) uint32_t*)l, 16, 0, 0);
}
DI void gload16u(const unsigned short* g, unsigned short* l) {
  __builtin_amdgcn_global_load_lds(
      (const __attribute__((address_space(1))) uint32_t*)g,
      (__attribute__((address_space(3))) uint32_t*)l, 16, 0, 0);
}
DI void gload4(const float* g, float* l) {
  __builtin_amdgcn_global_load_lds(
      (const __attribute__((address_space(1))) uint32_t*)g,
      (__attribute__((address_space(3))) uint32_t*)l, 4, 0, 0);
}

// ---- weight transpose+split (generalized): src fp32 [K][N] -> hi/lo bf16 [N][K] ----
struct TJob { const float* src; unsigned short* dh; unsigned short* dl;
              int N, K, ntn, tile_end; };
struct TJobs { TJob j[12]; };

__global__ __launch_bounds__(256) void wtrans(TJobs P) {
  __shared__ float t[64][65];
  int bx = blockIdx.x, ji = 0;
  while (ji < 11 && bx >= P.j[ji].tile_end) ++ji;
  TJob J = P.j[ji];
  int tix = bx - (ji ? P.j[ji - 1].tile_end : 0);
  int kt = tix / J.ntn, nt = tix % J.ntn;
  int k0 = kt * 64, n0 = nt * 64;
  int tid = threadIdx.x;
  #pragma unroll
  for (int p = 0; p < 16; ++p) {
    int flat = p * 256 + tid;
    int r = flat >> 6, c = flat & 63;
    int n = n0 + c;
    t[r][c] = (n < J.N && k0 + r < J.K) ? J.src[(size_t)(k0 + r) * J.N + n] : 0.0f;
  }
  __syncthreads();
  #pragma unroll
  for (int p = 0; p < 8; ++p) {
    int flat = p * 256 + tid;
    int rr = flat >> 5, cc = (flat & 31) * 2;
    if (n0 + rr < J.N && k0 + cc < J.K) {
      float w0v = t[cc][rr], w1v = t[cc + 1][rr];
      unsigned short h0 = f2bf(w0v), h1 = f2bf(w1v);
      us2v oh, ol;
      oh.x = h0; oh.y = h1;
      ol.x = f2bf(w0v - bf2f(h0));
      ol.y = f2bf(w1v - bf2f(h1));
      size_t off = (size_t)(n0 + rr) * J.K + k0 + cc;
      *(us2v*)(J.dh + off) = oh;
      *(us2v*)(J.dl + off) = ol;
    }
  }
}

// ---------- split-bf16 MFMA GEMM, 128x256 tile (r22 hot path; 3 blocks/CU) ----------
struct GJob {
  const float* A; const unsigned short* Wh; const unsigned short* Wl; float* C;
  const float* mixv; const float* shift; const float* bias;
  int N, K, ntn, kbeg, kend, atomicC, aact, epi, tile_end;
};
struct GJobs { GJob j[8]; };

__global__ __launch_bounds__(256, 3) void gemm_w256(GJobs P) {
  __shared__ unsigned short Ash[128][40];
  __shared__ unsigned short Asl[128][40];
  __shared__ unsigned short Bsh[256][32];
  __shared__ unsigned short Bsl[256][32];
  int bx = blockIdx.x, ji = 0;
  while (ji < 7 && bx >= P.j[ji].tile_end) ++ji;
  GJob J = P.j[ji];
  int tix = bx - (ji ? P.j[ji - 1].tile_end : 0);
  int mt = tix / J.ntn, nt = tix % J.ntn;
  int m0 = mt * 128, n0 = nt * 256;
  int tid = threadIdx.x;
  int lane = tid & 63, wid = tid >> 6;
  int wr = wid >> 1, wc = wid & 1;
  int l15 = lane & 15, lg = lane >> 4;
  f32x4 acc[4][8] = {};

  int sr = tid >> 3, skq = tid & 7;
  float ax[4][4], aq[4][4], amv[4];

  auto loadA = [&](int k0) {
    int kk = k0 + skq * 4;
    if (J.mixv) *(float4*)amv = *(const float4*)(J.mixv + kk);
    #pragma unroll
    for (int p = 0; p < 4; ++p) {
      int m = m0 + p * 32 + sr;
      const float* xp0 = J.A + (size_t)m * J.K + kk;
      *(float4*)ax[p] = *(const float4*)xp0;
      if (J.mixv) {
        const float* pp = ((m & (T_ - 1)) == 0)
            ? (J.shift + (size_t)(m >> 10) * C_ + kk)
            : (xp0 - C_);
        *(float4*)aq[p] = *(const float4*)pp;
      }
    }
  };
  auto writeA = [&]() {
    #pragma unroll
    for (int p = 0; p < 4; ++p) {
      us4v oh, ol;
      #pragma unroll
      for (int q = 0; q < 4; ++q) {
        float va = J.mixv ? (ax[p][q] + (aq[p][q] - ax[p][q]) * amv[q]) : ax[p][q];
        unsigned short hq = f2bf(va);
        oh[q] = hq;
        ol[q] = f2bf(va - bf2f(hq));
      }
      int r = p * 32 + sr;
      *(us4v*)&Ash[r][skq * 4] = oh;
      *(us4v*)&Asl[r][skq * 4] = ol;
    }
  };
  auto stageB = [&](int k0) {
    #pragma unroll
    for (int j = 0; j < 4; ++j) {
      int r0 = wid * 64 + j * 16;
      int rdst = r0 + (lane >> 2);
      int nrow = n0 + rdst;
      if (nrow >= J.N) nrow = J.N - 1;
      int ssrc = (lane & 3) ^ ((rdst >> 1) & 3);
      size_t gofs = (size_t)nrow * J.K + k0 + ssrc * 8;
      gload16u(J.Wh + gofs, &Bsh[r0][0]);
      gload16u(J.Wl + gofs, &Bsl[r0][0]);
    }
  };

  loadA(J.kbeg);
  stageB(J.kbeg);
  writeA();
  asm volatile("s_waitcnt vmcnt(0)" ::: "memory");
  __syncthreads();

  for (int k0 = J.kbeg; k0 < J.kend; k0 += 32) {
    bool more = (k0 + 32 < J.kend);
    if (more) loadA(k0 + 32);
    bf16x8 afh[4], afl[4];
    #pragma unroll
    for (int i = 0; i < 4; ++i) {
      int rr = wr * 64 + i * 16 + l15;
      afh[i] = __builtin_bit_cast(bf16x8, *(const us8v*)&Ash[rr][lg * 8]);
      afl[i] = __builtin_bit_cast(bf16x8, *(const us8v*)&Asl[rr][lg * 8]);
    }
    #pragma unroll
    for (int jn = 0; jn < 8; ++jn) {
      int rb = wc * 128 + jn * 16 + l15;
      int sl = (lg ^ ((rb >> 1) & 3)) * 8;
      bf16x8 bh = __builtin_bit_cast(bf16x8, *(const us8v*)&Bsh[rb][sl]);
      bf16x8 bl = __builtin_bit_cast(bf16x8, *(const us8v*)&Bsl[rb][sl]);
      #pragma unroll
      for (int i = 0; i < 4; ++i) {
        acc[i][jn] = __builtin_amdgcn_mfma_f32_16x16x32_bf16(afh[i], bh, acc[i][jn], 0, 0, 0);
        acc[i][jn] = __builtin_amdgcn_mfma_f32_16x16x32_bf16(afl[i], bh, acc[i][jn], 0, 0, 0);
        acc[i][jn] = __builtin_amdgcn_mfma_f32_16x16x32_bf16(afh[i], bl, acc[i][jn], 0, 0, 0);
      }
    }
    __syncthreads();
    if (more) { stageB(k0 + 32); writeA(); }
    asm volatile("s_waitcnt vmcnt(0)" ::: "memory");
    __syncthreads();
  }

  int orow0 = m0 + wr * 64 + 4 * lg;
  int ocol0 = n0 + wc * 128 + l15;
  #pragma unroll
  for (int i = 0; i < 4; ++i) {
    #pragma unroll
    for (int jn = 0; jn < 8; ++jn) {
      int col = ocol0 + jn * 16;
      if (col < J.N) {
        #pragma unroll
        for (int rr = 0; rr < 4; ++rr) {
          size_t idx = (size_t)(orow0 + i * 16 + rr) * J.N + col;
          float v = acc[i][jn][rr];
          if (J.atomicC) atomicAdd(&J.C[idx], v);
          else           J.C[idx] = v;
        }
      }
    }
  }
}

// ---------- gemm_up: same body + aact/epi/bias (G2 LoRA-up only, small-K) ----------
__global__ __launch_bounds__(256, 3) void gemm_up(GJobs P) {
  __shared__ unsigned short Ash[128][40];
  __shared__ unsigned short Asl[128][40];
  __shared__ unsigned short Bsh[256][32];
  __shared__ unsigned short Bsl[256][32];
  int bx = blockIdx.x, ji = 0;
  while (ji < 7 && bx >= P.j[ji].tile_end) ++ji;
  GJob J = P.j[ji];
  int tix = bx - (ji ? P.j[ji - 1].tile_end : 0);
  int mt = tix / J.ntn, nt = tix % J.ntn;
  int m0 = mt * 128, n0 = nt * 256;
  int tid = threadIdx.x;
  int lane = tid & 63, wid = tid >> 6;
  int wr = wid >> 1, wc = wid & 1;
  int l15 = lane & 15, lg = lane >> 4;
  f32x4 acc[4][8] = {};

  int sr = tid >> 3, skq = tid & 7;
  float ax[4][4];

  auto loadA = [&](int k0) {
    int kk = k0 + skq * 4;
    #pragma unroll
    for (int p = 0; p < 4; ++p) {
      int m = m0 + p * 32 + sr;
      *(float4*)ax[p] = *(const float4*)(J.A + (size_t)m * J.K + kk);
    }
  };
  auto writeA = [&]() {
    #pragma unroll
    for (int p = 0; p < 4; ++p) {
      us4v oh, ol;
      #pragma unroll
      for (int q = 0; q < 4; ++q) {
        float va = ax[p][q];
        if (J.aact == 1) va = tanhf(va);
        else if (J.aact == 2) va = sig_(va);
        unsigned short hq = f2bf(va);
        oh[q] = hq;
        ol[q] = f2bf(va - bf2f(hq));
      }
      int r = p * 32 + sr;
      *(us4v*)&Ash[r][skq * 4] = oh;
      *(us4v*)&Asl[r][skq * 4] = ol;
    }
  };
  auto stageB = [&](int k0) {
    #pragma unroll
    for (int j = 0; j < 4; ++j) {
      int r0 = wid * 64 + j * 16;
      int rdst = r0 + (lane >> 2);
      int nrow = n0 + rdst;
      if (nrow >= J.N) nrow = J.N - 1;
      int ssrc = (lane & 3) ^ ((rdst >> 1) & 3);
      size_t gofs = (size_t)nrow * J.K + k0 + ssrc * 8;
      gload16u(J.Wh + gofs, &Bsh[r0][0]);
      gload16u(J.Wl + gofs, &Bsl[r0][0]);
    }
  };

  loadA(J.kbeg);
  stageB(J.kbeg);
  writeA();
  asm volatile("s_waitcnt vmcnt(0)" ::: "memory");
  __syncthreads();

  for (int k0 = J.kbeg; k0 < J.kend; k0 += 32) {
    bool more = (k0 + 32 < J.kend);
    if (more) loadA(k0 + 32);
    bf16x8 afh[4], afl[4];
    #pragma unroll
    for (int i = 0; i < 4; ++i) {
      int rr = wr * 64 + i * 16 + l15;
      afh[i] = __builtin_bit_cast(bf16x8, *(const us8v*)&Ash[rr][lg * 8]);
      afl[i] = __builtin_bit_cast(bf16x8, *(const us8v*)&Asl[rr][lg * 8]);
    }
    #pragma unroll
    for (int jn = 0; jn < 8; ++jn) {
      int rb = wc * 128 + jn * 16 + l15;
      int sl = (lg ^ ((rb >> 1) & 3)) * 8;
      bf16x8 bh = __builtin_bit_cast(bf16x8, *(const us8v*)&Bsh[rb][sl]);
      bf16x8 bl = __builtin_bit_cast(bf16x8, *(const us8v*)&Bsl[rb][sl]);
      #pragma unroll
      for (int i = 0; i < 4; ++i) {
        acc[i][jn] = __builtin_amdgcn_mfma_f32_16x16x32_bf16(afh[i], bh, acc[i][jn], 0, 0, 0);
        acc[i][jn] = __builtin_amdgcn_mfma_f32_16x16x32_bf16(afl[i], bh, acc[i][jn], 0, 0, 0);
        acc[i][jn] = __builtin_amdgcn_mfma_f32_16x16x32_bf16(afh[i], bl, acc[i][jn], 0, 0, 0);
      }
    }
    __syncthreads();
    if (more) { stageB(k0 + 32); writeA(); }
    asm volatile("s_waitcnt vmcnt(0)" ::: "memory");
    __syncthreads();
  }

  int orow0 = m0 + wr * 64 + 4 * lg;
  int ocol0 = n0 + wc * 128 + l15;
  #pragma unroll
  for (int i = 0; i < 4; ++i) {
    #pragma unroll
    for (int jn = 0; jn < 8; ++jn) {
      int col = ocol0 + jn * 16;
      if (col < J.N) {
        #pragma unroll
        for (int rr = 0; rr < 4; ++rr) {
          size_t idx = (size_t)(orow0 + i * 16 + rr) * J.N + col;
          float v = acc[i][jn][rr];
          if (J.epi == 1) v = sig_(J.bias[col] + v);
          else if (J.epi == 2) v = 0.60653065971263342f * sig_(J.bias[col] + v);
          if (J.epi == 3) ((unsigned short*)J.C)[idx] = f2bf(v);
          else            J.C[idx] = v;
        }
      }
    }
  }
}

// ------- prescan v2: 16384 blocks x 256 thr (wave = head); shfl reductions -------
__global__ __launch_bounds__(256) void prescan(
    float* __restrict__ kio, float* __restrict__ vio,
    float* __restrict__ amat_ain, float* __restrict__ vmix_bin,
    const float* __restrict__ vfirst,
    const float* __restrict__ k_k, const float* __restrict__ k_a) {
  int gh = blockIdx.x * 4 + (threadIdx.x >> 6);
  int lane = threadIdx.x & 63;
  int h = gh & (H_ - 1);
  size_t base = (size_t)gh * 64 + lane;
  int cc = h * 64 + lane;
  float kv = kio[base];
  float kkv = kv * k_k[cc];
  float ss = kkv * kkv;
  ss += __shfl_xor(ss, 1);  ss += __shfl_xor(ss, 2);  ss += __shfl_xor(ss, 4);
  ss += __shfl_xor(ss, 8);  ss += __shfl_xor(ss, 16); ss += __shfl_xor(ss, 32);
  float nrm = fmaxf(sqrtf(ss), 1e-12f);
  float kkn = kkv / nrm;
  float av = amat_ain[base];
  float vmv = vmix_bin[base];
  float vv = vio[base];
  kio[base] = kv * (1.0f + (av - 1.0f) * k_a[cc]);
  vio[base] = vv + (vfirst[base] - vv) * vmv;
  amat_ain[base] = -kkn;
  vmix_bin[base] = kkn * av;
}

// ---- wkv scan v10: 8 time-segments x 2 v-halves; 1024 blocks x 512 thr ----
// chain 64 x seg 8 x vh 2; block covers 32 v-rows (8 waves x 4). Per-wave
// layout = v6 (vl = lane>>4, kq = lane&15, S[4]). seg s>0 warms up from zero
// over WU=96 steps. 22.5 KB LDS -> 4 blocks/CU, 32 waves/CU (full); longest
// block 224 steps (was 352).
static constexpr int CH = 8;
static constexpr int SEG = 128, WU = 96;

#define LOADSTEP(BUF, S_, Aa, Ww, Kk, Bb, Rr, Vt)                  \
  {                                                                \
    *(float4*)&Aa[0] = *(const float4*)&lds[BUF][3][S_][kb];       \
    *(float4*)&Ww[0] = *(const float4*)&lds[BUF][2][S_][kb];       \
    *(float4*)&Kk[0] = *(const float4*)&lds[BUF][1][S_][kb];       \
    *(float4*)&Bb[0] = *(const float4*)&lds[BUF][4][S_][kb];       \
    *(float4*)&Rr[0] = *(const float4*)&lds[BUF][0][S_][kb];       \
    Vt = vtl[BUF][S_][vr];                                         \
  }

#define COMPSTEP(Aa, Ww, Kk, Bb, Rr, Vt, TIDX)                              \
  {                                                                         \
    float p0 = S[0] * Aa[0], p1 = S[1] * Aa[1];                             \
    p0 = fmaf(S[2], Aa[2], p0);                                             \
    p1 = fmaf(S[3], Aa[3], p1);                                             \
    float sa = p0 + p1;                                                     \
    sa = dpp_xor1_add(sa);                                                  \
    sa = dpp_xor2_add(sa);                                                  \
    sa = dpp_hm_add(sa);                                                    \
    sa = dpp_mir_add(sa);                                                   \
    S[0] = fmaf(S[0], Ww[0], fmaf(Vt, Kk[0], sa * Bb[0]));                  \
    S[1] = fmaf(S[1], Ww[1], fmaf(Vt, Kk[1], sa * Bb[1]));                  \
    S[2] = fmaf(S[2], Ww[2], fmaf(Vt, Kk[2], sa * Bb[2]));                  \
    S[3] = fmaf(S[3], Ww[3], fmaf(Vt, Kk[3], sa * Bb[3]));                  \
    float y0 = S[0] * Rr[0], y1 = S[1] * Rr[1];                             \
    y0 = fmaf(S[2], Rr[2], y0);                                             \
    y1 = fmaf(S[3], Rr[3], y1);                                             \
    float y = y0 + y1;                                                      \
    y = dpp_xor1_add(y);                                                    \
    y = dpp_xor2_add(y);                                                    \
    y = dpp_hm_add(y);                                                      \
    y = dpp_mir_add(y);                                                     \
    if (kq == 0 && (TIDX) >= outfrom)                                       \
      obf[bh + (size_t)(TIDX)*2048 + v0 + vr] = f2bf(y);                    \
  }

__global__ __launch_bounds__(512) void wkv_scan_v10(
    const float* __restrict__ r, const float* __restrict__ k2,
    const float* __restrict__ w, const float* __restrict__ ain,
    const float* __restrict__ bin, const float* __restrict__ vp,
    const float* __restrict__ sInit, unsigned short* __restrict__ obf) {
  __shared__ float lds[2][5][CH][64];      // 20 KiB
  __shared__ float vtl[2][CH][32];         // 2 KiB
  int D = blockIdx.x;
  int chain = (D & 7) + 8 * (D >> 7);      // a chain's 16 blocks share D&7 -> one XCD
  int inner = (D >> 3) & 15;
  int seg = inner >> 1, vh = inner & 1;
  int b = chain >> 5, h = chain & 31;
  int v0 = vh * 32;
  int tid = threadIdx.x;
  int wid = tid >> 6, lane = tid & 63;
  int vl = lane >> 4, kq = lane & 15;
  int kb = kq * 4;
  int vr = wid * 4 + vl;                   // 0..31 within block
  size_t bh = (size_t)(b * T_) * 2048 + (size_t)h * 64;

  float S[4];
  if (seg == 0) {
    const float* sp = sInit + (((size_t)chain * 64 + v0 + vr) * 64) + kb;
    float4 s0 = *(const float4*)sp;
    S[0] = s0.x; S[1] = s0.y; S[2] = s0.z; S[3] = s0.w;
  } else {
    S[0] = S[1] = S[2] = S[3] = 0.0f;      // warmed up over WU steps
  }

  const float* arr[5] = {r, k2, w, ain, bin};

  // 10 main DMAs (array d>>1, t-half d&1) over 8 waves; vt by waves 0..3.
  auto stage = [&](int buf, int t0) {
    for (int d = wid; d < 10; d += 8) {
      int a = d >> 1, hf = d & 1;
      size_t gofs = bh + (size_t)(t0 + hf * 4 + (lane >> 4)) * 2048 + (lane & 15) * 4;
      gload16(arr[a] + gofs, &lds[buf][a][hf * 4][0]);
    }
    if (wid < 4) {                         // vt: 8 steps x 32 v; wave w -> steps [2w,2w+2)
      size_t gofs = bh + (size_t)(t0 + wid * 2 + (lane >> 5)) * 2048 + v0 + (lane & 31);
      gload4(vp + gofs, &vtl[buf][wid * 2][0]);
    }
  };

  int tstart = seg ? (seg * SEG - WU) : 0;
  int nch = (seg ? (SEG + WU) : SEG) / CH; // 28 or 16
  int outfrom = seg * SEG;

  stage(0, tstart);
  asm volatile("s_waitcnt vmcnt(0)" ::: "memory");
  __syncthreads();

  float A0[4], W0[4], K0[4], B0[4], R0[4], vt0;
  float A1[4], W1[4], K1[4], B1[4], R1[4], vt1;

  for (int c = 0; c < nch; ++c) {
    int cur = c & 1;
    int t0 = tstart + c * CH;
    if (c + 1 < nch) stage(cur ^ 1, t0 + CH);
    LOADSTEP(cur, 0, A0, W0, K0, B0, R0, vt0);
    #pragma unroll 2
    for (int s = 0; s < CH; s += 2) {
      LOADSTEP(cur, s + 1, A1, W1, K1, B1, R1, vt1);
      COMPSTEP(A0, W0, K0, B0, R0, vt0, t0 + s);
      if (s + 2 < CH) LOADSTEP(cur, s + 2, A0, W0, K0, B0, R0, vt0);
      COMPSTEP(A1, W1, K1, B1, R1, vt1, t0 + s + 1);
    }
    asm volatile("s_waitcnt vmcnt(0)" ::: "memory");
    __syncthreads();
  }
}

// ------- post v2: 16384 blocks x 256 thr (wave = head); shfl reductions, 0 barriers ----
__global__ __launch_bounds__(256) void post(
    const unsigned short* __restrict__ obf, const float* __restrict__ r,
    const float* __restrict__ k2, const float* __restrict__ vp,
    const unsigned short* __restrict__ gbf, const float* __restrict__ r_k,
    const float* __restrict__ lnw, const float* __restrict__ lnb,
    float* __restrict__ afin) {
  int gh = blockIdx.x * 4 + (threadIdx.x >> 6);
  int lane = threadIdx.x & 63;
  int h = gh & 31;
  size_t base = (size_t)gh * 64 + lane;
  int cc = h * 64 + lane;
  float ov = bf2f(obf[base]);
  float pr = r[base] * k2[base] * r_k[cc];
  float so = ov, so2 = ov * ov, sd = pr;
  #pragma unroll
  for (int d = 1; d <= 32; d <<= 1) {
    so  += __shfl_xor(so, d);
    so2 += __shfl_xor(so2, d);
    sd  += __shfl_xor(sd, d);
  }
  float mu = so * (1.0f / 64.0f);
  float var = so2 * (1.0f / 64.0f) - mu * mu;
  float on = (ov - mu) * rsqrtf(var + 6.4e-4f) * lnw[cc] + lnb[cc];
  float val = (on + sd * vp[base]) * bf2f(gbf[base]);
  afin[base] = val;
}

// ---------------- host ----------------
static constexpr size_t KB = 1024;
static constexpr size_t O_R    = 0;
static constexpr size_t O_K    = 16384;
static constexpr size_t O_V    = 32768;
static constexpr size_t O_WDEC = 49152;
static constexpr size_t O_AMAT = 65536;
static constexpr size_t O_VMIX = 81920;
static constexpr size_t O_AIN  = O_AMAT;
static constexpr size_t O_BIN  = O_VMIX;
static constexpr size_t O_AFIN = O_VMIX;
static constexpr size_t O_WRT_H = 49152, O_WRT_L = 57344;
static constexpr size_t O_WKT_H = 65536, O_WKT_L = 73728;
static constexpr size_t O_WVT_H = 81920, O_WVT_L = 90112;   // ends 98304
static constexpr size_t O_W1T_H = 98304, O_W1T_L = 98560;
static constexpr size_t O_A1T_H = 98816, O_A1T_L = 99072;
static constexpr size_t O_V1T_H = 99328, O_V1T_L = 99456;
static constexpr size_t O_G1T_H = 99584, O_G1T_L = 100096;  // ends 100608
static constexpr size_t O_WOT_H = 0, O_WOT_L = 8192;
// d_out layout (KB): gbf 0..8192 | HW2 8192 HA2 8704 HV2 9216 HG2 9472..10496
//   | up-weight planes 10496..12800 (dead before obf) | obf 8192..16384 (after scan)
static constexpr size_t D_W2T_H = 10496, D_W2T_L = 10752;
static constexpr size_t D_A2T_H = 11008, D_A2T_L = 11264;
static constexpr size_t D_V2T_H = 11520, D_V2T_L = 11648;
static constexpr size_t D_G2T_H = 11776, D_G2T_L = 12288;   // -> 12800

extern "C" void kernel_launch(void* const* d_in, const int* in_sizes, int n_in,
                              void* d_out, int out_size, void* d_ws, size_t ws_size,
                              hipStream_t stream) {
  const float* x      = (const float*)d_in[0];
  const float* vfirst = (const float*)d_in[1];
  const float* shift  = (const float*)d_in[2];
  const float* wkv0   = (const float*)d_in[3];
  const float* x_r = (const float*)d_in[4];
  const float* x_w = (const float*)d_in[5];
  const float* x_k = (const float*)d_in[6];
  const float* x_v = (const float*)d_in[7];
  const float* x_a = (const float*)d_in[8];
  const float* x_g = (const float*)d_in[9];
  const float* w0 = (const float*)d_in[10];
  const float* w1 = (const float*)d_in[11];
  const float* w2 = (const float*)d_in[12];
  const float* a0 = (const float*)d_in[13];
  const float* a1 = (const float*)d_in[14];
  const float* a2 = (const float*)d_in[15];
  const float* v0 = (const float*)d_in[16];
  const float* v1 = (const float*)d_in[17];
  const float* v2 = (const float*)d_in[18];
  const float* g1 = (const float*)d_in[19];
  const float* g2 = (const float*)d_in[20];
  const float* k_k = (const float*)d_in[21];
  const float* k_a = (const float*)d_in[22];
  const float* r_k = (const float*)d_in[23];
  const float* W_r = (const float*)d_in[24];
  const float* W_k = (const float*)d_in[25];
  const float* W_v = (const float*)d_in[26];
  const float* W_o = (const float*)d_in[27];
  const float* ln_w = (const float*)d_in[28];
  const float* ln_b = (const float*)d_in[29];

  char* ws = (char*)d_ws;
  auto F = [&](size_t kb) { return (float*)(ws + kb * KB); };
  auto U = [&](size_t kb) { return (unsigned short*)(ws + kb * KB); };
  auto D = [&](size_t kb) { return (unsigned short*)((char*)d_out + kb * KB); };
  float* outp = (float*)d_out;
  unsigned short* gbf = (unsigned short*)d_out;                       // 8 MiB
  unsigned short* obf = (unsigned short*)((char*)d_out + 8192 * KB);  // 8 MiB
  float* HW2 = (float*)((char*)d_out + 8192 * KB);                    // 512 KiB
  float* HA2 = (float*)((char*)d_out + 8704 * KB);                    // 512 KiB
  float* HV2 = (float*)((char*)d_out + 9216 * KB);                    // 256 KiB
  float* HG2 = (float*)((char*)d_out + 9472 * KB);                    // 1024 KiB

  // T1: transpose+split all 11 weights (downs into ws, ups into d_out tail).
  {
    TJobs TG{};
    int cum = 0, i = 0;
    auto addT = [&](const float* src, unsigned short* dh, unsigned short* dl,
                    int N, int K) {
      int ntn = (N + 63) / 64;
      cum += ((K + 63) / 64) * ntn;
      TG.j[i++] = TJob{src, dh, dl, N, K, ntn, cum};
    };
    addT(W_r, U(O_WRT_H), U(O_WRT_L), 2048, 2048);
    addT(W_k, U(O_WKT_H), U(O_WKT_L), 2048, 2048);
    addT(W_v, U(O_WVT_H), U(O_WVT_L), 2048, 2048);
    addT(w1, U(O_W1T_H), U(O_W1T_L), 64, 2048);
    addT(a1, U(O_A1T_H), U(O_A1T_L), 64, 2048);
    addT(v1, U(O_V1T_H), U(O_V1T_L), 32, 2048);
    addT(g1, U(O_G1T_H), U(O_G1T_L), 128, 2048);
    addT(w2, D(D_W2T_H), D(D_W2T_L), 2048, 64);
    addT(a2, D(D_A2T_H), D(D_A2T_L), 2048, 64);
    addT(v2, D(D_V2T_H), D(D_V2T_L), 2048, 32);
    addT(g2, D(D_G2T_H), D(D_G2T_L), 2048, 128);
    wtrans<<<dim3(cum), dim3(256), 0, stream>>>(TG);
  }

  // G1 (gemm_w256): r,k,v + 4 LoRA-downs with fused token-shift mixes.
  {
    GJobs G{};
    int cum = 0, i = 0;
    auto add = [&](size_t hkb, size_t lkb, float* Cp, const float* mixv, int N) {
      int ntn = (N + 255) / 256;
      cum += 16 * ntn;
      G.j[i++] = GJob{x, U(hkb), U(lkb), Cp, mixv, shift, nullptr,
                      N, 2048, ntn, 0, 2048, 0, 0, 0, cum};
    };
    add(O_WRT_H, O_WRT_L, F(O_R), x_r, 2048);
    add(O_WKT_H, O_WKT_L, F(O_K), x_k, 2048);
    add(O_WVT_H, O_WVT_L, F(O_V), x_v, 2048);
    add(O_W1T_H, O_W1T_L, HW2, x_w, 64);
    add(O_A1T_H, O_A1T_L, HA2, x_a, 64);
    add(O_V1T_H, O_V1T_L, HV2, x_v, 32);
    add(O_G1T_H, O_G1T_L, HG2, x_g, 128);
    gemm_w256<<<dim3(cum), dim3(256), 0, stream>>>(G);
  }

  // G2 (gemm_up, small-K): LoRA-up with fused activations/epilogues.
  {
    GJobs G{};
    int cum = 0, i = 0;
    auto add = [&](const float* A, size_t whkb, size_t wlkb, float* Cp,
                   const float* bias, int K, int aact, int epi) {
      cum += 16 * 8;
      G.j[i++] = GJob{A, D(whkb), D(wlkb), Cp, nullptr, nullptr, bias,
                      2048, K, 8, 0, K, 0, aact, epi, cum};
    };
    add(HW2, D_W2T_H, D_W2T_L, F(O_WDEC), w0, 64, 1, 2);
    add(HA2, D_A2T_H, D_A2T_L, F(O_AMAT), a0, 64, 0, 1);
    add(HV2, D_V2T_H, D_V2T_L, F(O_VMIX), v0, 32, 0, 1);
    add(HG2, D_G2T_H, D_G2T_L, (float*)gbf, nullptr, 128, 2, 3);
    gemm_up<<<dim3(cum), dim3(256), 0, stream>>>(G);
  }

  // prescan v2.
  prescan<<<dim3(16384), dim3(256), 0, stream>>>(F(O_K), F(O_V), F(O_AMAT), F(O_VMIX),
                                                 vfirst, k_k, k_a);

  // scan v10: 1024 blocks x 512 threads (8 segments x 2 v-halves, 96-step warmup).
  wkv_scan_v10<<<dim3(1024), dim3(512), 0, stream>>>(F(O_R), F(O_K), F(O_WDEC), F(O_AIN),
                                                     F(O_BIN), F(O_V), wkv0, obf);

  // post v2.
  post<<<dim3(16384), dim3(256), 0, stream>>>(obf, F(O_R), F(O_K), F(O_V),
                                              gbf, r_k, ln_w, ln_b, F(O_AFIN));

  // d_out consumed by post -> zero it for G3's split-K atomic accumulation.
  hipMemsetAsync(d_out, 0, (size_t)16384 * KB, stream);

  // T2: W_o transpose+split into dead r region.
  {
    TJobs TO{};
    TO.j[0] = TJob{W_o, U(O_WOT_H), U(O_WOT_L), 2048, 2048, 32, 1024};
    wtrans<<<dim3(1024), dim3(256), 0, stream>>>(TO);
  }

  // G3 (gemm_w256, split-K 4, atomic): out = afin @ W_o. Grid == last tile_end.
  {
    GJobs G{};
    G.j[0] = GJob{F(O_AFIN), U(O_WOT_H), U(O_WOT_L), outp, nullptr, nullptr, nullptr,
                  2048, 2048, 8, 0, 512, 1, 0, 0, 128};
    G.j[1] = GJob{F(O_AFIN), U(O_WOT_H), U(O_WOT_L), outp, nullptr, nullptr, nullptr,
                  2048, 2048, 8, 512, 1024, 1, 0, 0, 256};
    G.j[2] = GJob{F(O_AFIN), U(O_WOT_H), U(O_WOT_L), outp, nullptr, nullptr, nullptr,
                  2048, 2048, 8, 1024, 1536, 1, 0, 0, 384};
    G.j[3] = GJob{F(O_AFIN), U(O_WOT_H), U(O_WOT_L), outp, nullptr, nullptr, nullptr,
                  2048, 2048, 8, 1536, 2048, 1, 0, 0, 512};
    gemm_w256<<<dim3(512), dim3(256), 0, stream>>>(G);
  }

  (void)in_sizes; (void)n_in; (void)out_size; (void)ws_size;
}

// Round 21
// 720.717 us; speedup vs baseline: 2.1503x; 2.1503x over previous
//
#include <hip/hip_runtime.h>
#include <cstdint>
#include <cstddef>

// RWKV-7 Tmix forward, MI355X gfx950 — ROUND 25: revert launch_bounds to (256,2).
// r24 lesson: __launch_bounds__(256,3) made the allocator cap VGPR at 84 — below
// the 128-reg accumulator floor -> acc spilled to scratch (FETCH 100MB->1.2GB,
// WRITE 51MB->1.5GB, G1 217->900 µs). The hint is a register-allocator directive
// first; 84 < acc floor = catastrophic. Fix: (256,2) restored on both GEMM
// kernels (proven VGPR=128, no spill). Scan v10 kept (register-light, sound
// critical-path math: 224 vs 352 steps) — this round isolates its effect.

#define DI __device__ __forceinline__
static constexpr int T_ = 1024, C_ = 2048, H_ = 32;

typedef __attribute__((ext_vector_type(8))) __bf16 bf16x8;
typedef __attribute__((ext_vector_type(4))) float f32x4;
typedef __attribute__((ext_vector_type(8))) unsigned short us8v;
typedef __attribute__((ext_vector_type(4))) unsigned short us4v;
typedef __attribute__((ext_vector_type(2))) unsigned short us2v;

DI float sig_(float z) { return 1.0f / (1.0f + expf(-z)); }

DI unsigned short f2bf(float f) {           // round-to-nearest-even f32 -> bf16
  union { float f; uint32_t u; } v; v.f = f;
  uint32_t u = v.u;
  return (unsigned short)((u + 0x7FFFu + ((u >> 16) & 1u)) >> 16);
}
DI float bf2f(unsigned short h) {
  union { uint32_t u; float f; } v; v.u = ((uint32_t)h) << 16;
  return v.f;
}

// DPP butterfly adds over 16 k-lanes (kq = lane&15).
DI float dpp_xor1_add(float x) {
  int r = __builtin_amdgcn_update_dpp(0, __float_as_int(x), 0xB1, 0xF, 0xF, true);
  return x + __int_as_float(r);
}
DI float dpp_xor2_add(float x) {
  int r = __builtin_amdgcn_update_dpp(0, __float_as_int(x), 0x4E, 0xF, 0xF, true);
  return x + __int_as_float(r);
}
DI float dpp_hm_add(float x) {
  int r = __builtin_amdgcn_update_dpp(0, __float_as_int(x), 0x141, 0xF, 0xF, true);
  return x + __int_as_float(r);
}
DI float dpp_mir_add(float x) {
  int r = __builtin_amdgcn_update_dpp(0, __float_as_int(x), 0x140, 0xF, 0xF, true);
  return x + __int_as_float(r);
}

// async global -> LDS DMA (dest = wave-uniform base + lane*size).
DI void gload16(const float* g, float* l) {
  __builtin_amdgcn_global_load_lds(
      (const __attribute__((address_space(1))) uint32_t*)g,
      (__attribute__((address_space(3))) uint32_t*)l, 16, 0, 0);
}
DI void gload16u(const unsigned short* g, unsigned short* l) {
  __builtin_amdgcn_global_load_lds(
      (const __attribute__((address_space(1))) uint32_t*)g,
      (__attribute__((address_space(3))) uint32_t*)l, 16, 0, 0);
}
DI void gload4(const float* g, float* l) {
  __builtin_amdgcn_global_load_lds(
      (const __attribute__((address_space(1))) uint32_t*)g,
      (__attribute__((address_space(3))) uint32_t*)l, 4, 0, 0);
}

// ---- weight transpose+split (generalized): src fp32 [K][N] -> hi/lo bf16 [N][K] ----
struct TJob { const float* src; unsigned short* dh; unsigned short* dl;
              int N, K, ntn, tile_end; };
struct TJobs { TJob j[12]; };

__global__ __launch_bounds__(256) void wtrans(TJobs P) {
  __shared__ float t[64][65];
  int bx = blockIdx.x, ji = 0;
  while (ji < 11 && bx >= P.j[ji].tile_end) ++ji;
  TJob J = P.j[ji];
  int tix = bx - (ji ? P.j[ji - 1].tile_end : 0);
  int kt = tix / J.ntn, nt = tix % J.ntn;
  int k0 = kt * 64, n0 = nt * 64;
  int tid = threadIdx.x;
  #pragma unroll
  for (int p = 0; p < 16; ++p) {
    int flat = p * 256 + tid;
    int r = flat >> 6, c = flat & 63;
    int n = n0 + c;
    t[r][c] = (n < J.N && k0 + r < J.K) ? J.src[(size_t)(k0 + r) * J.N + n] : 0.0f;
  }
  __syncthreads();
  #pragma unroll
  for (int p = 0; p < 8; ++p) {
    int flat = p * 256 + tid;
    int rr = flat >> 5, cc = (flat & 31) * 2;
    if (n0 + rr < J.N && k0 + cc < J.K) {
      float w0v = t[cc][rr], w1v = t[cc + 1][rr];
      unsigned short h0 = f2bf(w0v), h1 = f2bf(w1v);
      us2v oh, ol;
      oh.x = h0; oh.y = h1;
      ol.x = f2bf(w0v - bf2f(h0));
      ol.y = f2bf(w1v - bf2f(h1));
      size_t off = (size_t)(n0 + rr) * J.K + k0 + cc;
      *(us2v*)(J.dh + off) = oh;
      *(us2v*)(J.dl + off) = ol;
    }
  }
}

// ---------- split-bf16 MFMA GEMM, 128x256 tile (r22 hot path, (256,2)) ----------
struct GJob {
  const float* A; const unsigned short* Wh; const unsigned short* Wl; float* C;
  const float* mixv; const float* shift; const float* bias;
  int N, K, ntn, kbeg, kend, atomicC, aact, epi, tile_end;
};
struct GJobs { GJob j[8]; };

__global__ __launch_bounds__(256, 2) void gemm_w256(GJobs P) {
  __shared__ unsigned short Ash[128][40];
  __shared__ unsigned short Asl[128][40];
  __shared__ unsigned short Bsh[256][32];
  __shared__ unsigned short Bsl[256][32];
  int bx = blockIdx.x, ji = 0;
  while (ji < 7 && bx >= P.j[ji].tile_end) ++ji;
  GJob J = P.j[ji];
  int tix = bx - (ji ? P.j[ji - 1].tile_end : 0);
  int mt = tix / J.ntn, nt = tix % J.ntn;
  int m0 = mt * 128, n0 = nt * 256;
  int tid = threadIdx.x;
  int lane = tid & 63, wid = tid >> 6;
  int wr = wid >> 1, wc = wid & 1;
  int l15 = lane & 15, lg = lane >> 4;
  f32x4 acc[4][8] = {};

  int sr = tid >> 3, skq = tid & 7;
  float ax[4][4], aq[4][4], amv[4];

  auto loadA = [&](int k0) {
    int kk = k0 + skq * 4;
    if (J.mixv) *(float4*)amv = *(const float4*)(J.mixv + kk);
    #pragma unroll
    for (int p = 0; p < 4; ++p) {
      int m = m0 + p * 32 + sr;
      const float* xp0 = J.A + (size_t)m * J.K + kk;
      *(float4*)ax[p] = *(const float4*)xp0;
      if (J.mixv) {
        const float* pp = ((m & (T_ - 1)) == 0)
            ? (J.shift + (size_t)(m >> 10) * C_ + kk)
            : (xp0 - C_);
        *(float4*)aq[p] = *(const float4*)pp;
      }
    }
  };
  auto writeA = [&]() {
    #pragma unroll
    for (int p = 0; p < 4; ++p) {
      us4v oh, ol;
      #pragma unroll
      for (int q = 0; q < 4; ++q) {
        float va = J.mixv ? (ax[p][q] + (aq[p][q] - ax[p][q]) * amv[q]) : ax[p][q];
        unsigned short hq = f2bf(va);
        oh[q] = hq;
        ol[q] = f2bf(va - bf2f(hq));
      }
      int r = p * 32 + sr;
      *(us4v*)&Ash[r][skq * 4] = oh;
      *(us4v*)&Asl[r][skq * 4] = ol;
    }
  };
  auto stageB = [&](int k0) {
    #pragma unroll
    for (int j = 0; j < 4; ++j) {
      int r0 = wid * 64 + j * 16;
      int rdst = r0 + (lane >> 2);
      int nrow = n0 + rdst;
      if (nrow >= J.N) nrow = J.N - 1;
      int ssrc = (lane & 3) ^ ((rdst >> 1) & 3);
      size_t gofs = (size_t)nrow * J.K + k0 + ssrc * 8;
      gload16u(J.Wh + gofs, &Bsh[r0][0]);
      gload16u(J.Wl + gofs, &Bsl[r0][0]);
    }
  };

  loadA(J.kbeg);
  stageB(J.kbeg);
  writeA();
  asm volatile("s_waitcnt vmcnt(0)" ::: "memory");
  __syncthreads();

  for (int k0 = J.kbeg; k0 < J.kend; k0 += 32) {
    bool more = (k0 + 32 < J.kend);
    if (more) loadA(k0 + 32);
    bf16x8 afh[4], afl[4];
    #pragma unroll
    for (int i = 0; i < 4; ++i) {
      int rr = wr * 64 + i * 16 + l15;
      afh[i] = __builtin_bit_cast(bf16x8, *(const us8v*)&Ash[rr][lg * 8]);
      afl[i] = __builtin_bit_cast(bf16x8, *(const us8v*)&Asl[rr][lg * 8]);
    }
    #pragma unroll
    for (int jn = 0; jn < 8; ++jn) {
      int rb = wc * 128 + jn * 16 + l15;
      int sl = (lg ^ ((rb >> 1) & 3)) * 8;
      bf16x8 bh = __builtin_bit_cast(bf16x8, *(const us8v*)&Bsh[rb][sl]);
      bf16x8 bl = __builtin_bit_cast(bf16x8, *(const us8v*)&Bsl[rb][sl]);
      #pragma unroll
      for (int i = 0; i < 4; ++i) {
        acc[i][jn] = __builtin_amdgcn_mfma_f32_16x16x32_bf16(afh[i], bh, acc[i][jn], 0, 0, 0);
        acc[i][jn] = __builtin_amdgcn_mfma_f32_16x16x32_bf16(afl[i], bh, acc[i][jn], 0, 0, 0);
        acc[i][jn] = __builtin_amdgcn_mfma_f32_16x16x32_bf16(afh[i], bl, acc[i][jn], 0, 0, 0);
      }
    }
    __syncthreads();
    if (more) { stageB(k0 + 32); writeA(); }
    asm volatile("s_waitcnt vmcnt(0)" ::: "memory");
    __syncthreads();
  }

  int orow0 = m0 + wr * 64 + 4 * lg;
  int ocol0 = n0 + wc * 128 + l15;
  #pragma unroll
  for (int i = 0; i < 4; ++i) {
    #pragma unroll
    for (int jn = 0; jn < 8; ++jn) {
      int col = ocol0 + jn * 16;
      if (col < J.N) {
        #pragma unroll
        for (int rr = 0; rr < 4; ++rr) {
          size_t idx = (size_t)(orow0 + i * 16 + rr) * J.N + col;
          float v = acc[i][jn][rr];
          if (J.atomicC) atomicAdd(&J.C[idx], v);
          else           J.C[idx] = v;
        }
      }
    }
  }
}

// ---------- gemm_up: same body + aact/epi/bias (G2 LoRA-up only, small-K) ----------
__global__ __launch_bounds__(256, 2) void gemm_up(GJobs P) {
  __shared__ unsigned short Ash[128][40];
  __shared__ unsigned short Asl[128][40];
  __shared__ unsigned short Bsh[256][32];
  __shared__ unsigned short Bsl[256][32];
  int bx = blockIdx.x, ji = 0;
  while (ji < 7 && bx >= P.j[ji].tile_end) ++ji;
  GJob J = P.j[ji];
  int tix = bx - (ji ? P.j[ji - 1].tile_end : 0);
  int mt = tix / J.ntn, nt = tix % J.ntn;
  int m0 = mt * 128, n0 = nt * 256;
  int tid = threadIdx.x;
  int lane = tid & 63, wid = tid >> 6;
  int wr = wid >> 1, wc = wid & 1;
  int l15 = lane & 15, lg = lane >> 4;
  f32x4 acc[4][8] = {};

  int sr = tid >> 3, skq = tid & 7;
  float ax[4][4];

  auto loadA = [&](int k0) {
    int kk = k0 + skq * 4;
    #pragma unroll
    for (int p = 0; p < 4; ++p) {
      int m = m0 + p * 32 + sr;
      *(float4*)ax[p] = *(const float4*)(J.A + (size_t)m * J.K + kk);
    }
  };
  auto writeA = [&]() {
    #pragma unroll
    for (int p = 0; p < 4; ++p) {
      us4v oh, ol;
      #pragma unroll
      for (int q = 0; q < 4; ++q) {
        float va = ax[p][q];
        if (J.aact == 1) va = tanhf(va);
        else if (J.aact == 2) va = sig_(va);
        unsigned short hq = f2bf(va);
        oh[q] = hq;
        ol[q] = f2bf(va - bf2f(hq));
      }
      int r = p * 32 + sr;
      *(us4v*)&Ash[r][skq * 4] = oh;
      *(us4v*)&Asl[r][skq * 4] = ol;
    }
  };
  auto stageB = [&](int k0) {
    #pragma unroll
    for (int j = 0; j < 4; ++j) {
      int r0 = wid * 64 + j * 16;
      int rdst = r0 + (lane >> 2);
      int nrow = n0 + rdst;
      if (nrow >= J.N) nrow = J.N - 1;
      int ssrc = (lane & 3) ^ ((rdst >> 1) & 3);
      size_t gofs = (size_t)nrow * J.K + k0 + ssrc * 8;
      gload16u(J.Wh + gofs, &Bsh[r0][0]);
      gload16u(J.Wl + gofs, &Bsl[r0][0]);
    }
  };

  loadA(J.kbeg);
  stageB(J.kbeg);
  writeA();
  asm volatile("s_waitcnt vmcnt(0)" ::: "memory");
  __syncthreads();

  for (int k0 = J.kbeg; k0 < J.kend; k0 += 32) {
    bool more = (k0 + 32 < J.kend);
    if (more) loadA(k0 + 32);
    bf16x8 afh[4], afl[4];
    #pragma unroll
    for (int i = 0; i < 4; ++i) {
      int rr = wr * 64 + i * 16 + l15;
      afh[i] = __builtin_bit_cast(bf16x8, *(const us8v*)&Ash[rr][lg * 8]);
      afl[i] = __builtin_bit_cast(bf16x8, *(const us8v*)&Asl[rr][lg * 8]);
    }
    #pragma unroll
    for (int jn = 0; jn < 8; ++jn) {
      int rb = wc * 128 + jn * 16 + l15;
      int sl = (lg ^ ((rb >> 1) & 3)) * 8;
      bf16x8 bh = __builtin_bit_cast(bf16x8, *(const us8v*)&Bsh[rb][sl]);
      bf16x8 bl = __builtin_bit_cast(bf16x8, *(const us8v*)&Bsl[rb][sl]);
      #pragma unroll
      for (int i = 0; i < 4; ++i) {
        acc[i][jn] = __builtin_amdgcn_mfma_f32_16x16x32_bf16(afh[i], bh, acc[i][jn], 0, 0, 0);
        acc[i][jn] = __builtin_amdgcn_mfma_f32_16x16x32_bf16(afl[i], bh, acc[i][jn], 0, 0, 0);
        acc[i][jn] = __builtin_amdgcn_mfma_f32_16x16x32_bf16(afh[i], bl, acc[i][jn], 0, 0, 0);
      }
    }
    __syncthreads();
    if (more) { stageB(k0 + 32); writeA(); }
    asm volatile("s_waitcnt vmcnt(0)" ::: "memory");
    __syncthreads();
  }

  int orow0 = m0 + wr * 64 + 4 * lg;
  int ocol0 = n0 + wc * 128 + l15;
  #pragma unroll
  for (int i = 0; i < 4; ++i) {
    #pragma unroll
    for (int jn = 0; jn < 8; ++jn) {
      int col = ocol0 + jn * 16;
      if (col < J.N) {
        #pragma unroll
        for (int rr = 0; rr < 4; ++rr) {
          size_t idx = (size_t)(orow0 + i * 16 + rr) * J.N + col;
          float v = acc[i][jn][rr];
          if (J.epi == 1) v = sig_(J.bias[col] + v);
          else if (J.epi == 2) v = 0.60653065971263342f * sig_(J.bias[col] + v);
          if (J.epi == 3) ((unsigned short*)J.C)[idx] = f2bf(v);
          else            J.C[idx] = v;
        }
      }
    }
  }
}

// ------- prescan v2: 16384 blocks x 256 thr (wave = head); shfl reductions -------
__global__ __launch_bounds__(256) void prescan(
    float* __restrict__ kio, float* __restrict__ vio,
    float* __restrict__ amat_ain, float* __restrict__ vmix_bin,
    const float* __restrict__ vfirst,
    const float* __restrict__ k_k, const float* __restrict__ k_a) {
  int gh = blockIdx.x * 4 + (threadIdx.x >> 6);
  int lane = threadIdx.x & 63;
  int h = gh & (H_ - 1);
  size_t base = (size_t)gh * 64 + lane;
  int cc = h * 64 + lane;
  float kv = kio[base];
  float kkv = kv * k_k[cc];
  float ss = kkv * kkv;
  ss += __shfl_xor(ss, 1);  ss += __shfl_xor(ss, 2);  ss += __shfl_xor(ss, 4);
  ss += __shfl_xor(ss, 8);  ss += __shfl_xor(ss, 16); ss += __shfl_xor(ss, 32);
  float nrm = fmaxf(sqrtf(ss), 1e-12f);
  float kkn = kkv / nrm;
  float av = amat_ain[base];
  float vmv = vmix_bin[base];
  float vv = vio[base];
  kio[base] = kv * (1.0f + (av - 1.0f) * k_a[cc]);
  vio[base] = vv + (vfirst[base] - vv) * vmv;
  amat_ain[base] = -kkn;
  vmix_bin[base] = kkn * av;
}

// ---- wkv scan v10: 8 time-segments x 2 v-halves; 1024 blocks x 512 thr ----
static constexpr int CH = 8;
static constexpr int SEG = 128, WU = 96;

#define LOADSTEP(BUF, S_, Aa, Ww, Kk, Bb, Rr, Vt)                  \
  {                                                                \
    *(float4*)&Aa[0] = *(const float4*)&lds[BUF][3][S_][kb];       \
    *(float4*)&Ww[0] = *(const float4*)&lds[BUF][2][S_][kb];       \
    *(float4*)&Kk[0] = *(const float4*)&lds[BUF][1][S_][kb];       \
    *(float4*)&Bb[0] = *(const float4*)&lds[BUF][4][S_][kb];       \
    *(float4*)&Rr[0] = *(const float4*)&lds[BUF][0][S_][kb];       \
    Vt = vtl[BUF][S_][vr];                                         \
  }

#define COMPSTEP(Aa, Ww, Kk, Bb, Rr, Vt, TIDX)                              \
  {                                                                         \
    float p0 = S[0] * Aa[0], p1 = S[1] * Aa[1];                             \
    p0 = fmaf(S[2], Aa[2], p0);                                             \
    p1 = fmaf(S[3], Aa[3], p1);                                             \
    float sa = p0 + p1;                                                     \
    sa = dpp_xor1_add(sa);                                                  \
    sa = dpp_xor2_add(sa);                                                  \
    sa = dpp_hm_add(sa);                                                    \
    sa = dpp_mir_add(sa);                                                   \
    S[0] = fmaf(S[0], Ww[0], fmaf(Vt, Kk[0], sa * Bb[0]));                  \
    S[1] = fmaf(S[1], Ww[1], fmaf(Vt, Kk[1], sa * Bb[1]));                  \
    S[2] = fmaf(S[2], Ww[2], fmaf(Vt, Kk[2], sa * Bb[2]));                  \
    S[3] = fmaf(S[3], Ww[3], fmaf(Vt, Kk[3], sa * Bb[3]));                  \
    float y0 = S[0] * Rr[0], y1 = S[1] * Rr[1];                             \
    y0 = fmaf(S[2], Rr[2], y0);                                             \
    y1 = fmaf(S[3], Rr[3], y1);                                             \
    float y = y0 + y1;                                                      \
    y = dpp_xor1_add(y);                                                    \
    y = dpp_xor2_add(y);                                                    \
    y = dpp_hm_add(y);                                                      \
    y = dpp_mir_add(y);                                                     \
    if (kq == 0 && (TIDX) >= outfrom)                                       \
      obf[bh + (size_t)(TIDX)*2048 + v0 + vr] = f2bf(y);                    \
  }

__global__ __launch_bounds__(512) void wkv_scan_v10(
    const float* __restrict__ r, const float* __restrict__ k2,
    const float* __restrict__ w, const float* __restrict__ ain,
    const float* __restrict__ bin, const float* __restrict__ vp,
    const float* __restrict__ sInit, unsigned short* __restrict__ obf) {
  __shared__ float lds[2][5][CH][64];      // 20 KiB
  __shared__ float vtl[2][CH][32];         // 2 KiB
  int D = blockIdx.x;
  int chain = (D & 7) + 8 * (D >> 7);      // a chain's 16 blocks share D&7 -> one XCD
  int inner = (D >> 3) & 15;
  int seg = inner >> 1, vh = inner & 1;
  int b = chain >> 5, h = chain & 31;
  int v0 = vh * 32;
  int tid = threadIdx.x;
  int wid = tid >> 6, lane = tid & 63;
  int vl = lane >> 4, kq = lane & 15;
  int kb = kq * 4;
  int vr = wid * 4 + vl;                   // 0..31 within block
  size_t bh = (size_t)(b * T_) * 2048 + (size_t)h * 64;

  float S[4];
  if (seg == 0) {
    const float* sp = sInit + (((size_t)chain * 64 + v0 + vr) * 64) + kb;
    float4 s0 = *(const float4*)sp;
    S[0] = s0.x; S[1] = s0.y; S[2] = s0.z; S[3] = s0.w;
  } else {
    S[0] = S[1] = S[2] = S[3] = 0.0f;      // warmed up over WU steps
  }

  const float* arr[5] = {r, k2, w, ain, bin};

  auto stage = [&](int buf, int t0) {
    for (int d = wid; d < 10; d += 8) {
      int a = d >> 1, hf = d & 1;
      size_t gofs = bh + (size_t)(t0 + hf * 4 + (lane >> 4)) * 2048 + (lane & 15) * 4;
      gload16(arr[a] + gofs, &lds[buf][a][hf * 4][0]);
    }
    if (wid < 4) {
      size_t gofs = bh + (size_t)(t0 + wid * 2 + (lane >> 5)) * 2048 + v0 + (lane & 31);
      gload4(vp + gofs, &vtl[buf][wid * 2][0]);
    }
  };

  int tstart = seg ? (seg * SEG - WU) : 0;
  int nch = (seg ? (SEG + WU) : SEG) / CH; // 28 or 16
  int outfrom = seg * SEG;

  stage(0, tstart);
  asm volatile("s_waitcnt vmcnt(0)" ::: "memory");
  __syncthreads();

  float A0[4], W0[4], K0[4], B0[4], R0[4], vt0;
  float A1[4], W1[4], K1[4], B1[4], R1[4], vt1;

  for (int c = 0; c < nch; ++c) {
    int cur = c & 1;
    int t0 = tstart + c * CH;
    if (c + 1 < nch) stage(cur ^ 1, t0 + CH);
    LOADSTEP(cur, 0, A0, W0, K0, B0, R0, vt0);
    #pragma unroll 2
    for (int s = 0; s < CH; s += 2) {
      LOADSTEP(cur, s + 1, A1, W1, K1, B1, R1, vt1);
      COMPSTEP(A0, W0, K0, B0, R0, vt0, t0 + s);
      if (s + 2 < CH) LOADSTEP(cur, s + 2, A0, W0, K0, B0, R0, vt0);
      COMPSTEP(A1, W1, K1, B1, R1, vt1, t0 + s + 1);
    }
    asm volatile("s_waitcnt vmcnt(0)" ::: "memory");
    __syncthreads();
  }
}

// ------- post v2: 16384 blocks x 256 thr (wave = head); shfl reductions, 0 barriers ----
__global__ __launch_bounds__(256) void post(
    const unsigned short* __restrict__ obf, const float* __restrict__ r,
    const float* __restrict__ k2, const float* __restrict__ vp,
    const unsigned short* __restrict__ gbf, const float* __restrict__ r_k,
    const float* __restrict__ lnw, const float* __restrict__ lnb,
    float* __restrict__ afin) {
  int gh = blockIdx.x * 4 + (threadIdx.x >> 6);
  int lane = threadIdx.x & 63;
  int h = gh & 31;
  size_t base = (size_t)gh * 64 + lane;
  int cc = h * 64 + lane;
  float ov = bf2f(obf[base]);
  float pr = r[base] * k2[base] * r_k[cc];
  float so = ov, so2 = ov * ov, sd = pr;
  #pragma unroll
  for (int d = 1; d <= 32; d <<= 1) {
    so  += __shfl_xor(so, d);
    so2 += __shfl_xor(so2, d);
    sd  += __shfl_xor(sd, d);
  }
  float mu = so * (1.0f / 64.0f);
  float var = so2 * (1.0f / 64.0f) - mu * mu;
  float on = (ov - mu) * rsqrtf(var + 6.4e-4f) * lnw[cc] + lnb[cc];
  float val = (on + sd * vp[base]) * bf2f(gbf[base]);
  afin[base] = val;
}

// ---------------- host ----------------
static constexpr size_t KB = 1024;
static constexpr size_t O_R    = 0;
static constexpr size_t O_K    = 16384;
static constexpr size_t O_V    = 32768;
static constexpr size_t O_WDEC = 49152;
static constexpr size_t O_AMAT = 65536;
static constexpr size_t O_VMIX = 81920;
static constexpr size_t O_AIN  = O_AMAT;
static constexpr size_t O_BIN  = O_VMIX;
static constexpr size_t O_AFIN = O_VMIX;
static constexpr size_t O_WRT_H = 49152, O_WRT_L = 57344;
static constexpr size_t O_WKT_H = 65536, O_WKT_L = 73728;
static constexpr size_t O_WVT_H = 81920, O_WVT_L = 90112;   // ends 98304
static constexpr size_t O_W1T_H = 98304, O_W1T_L = 98560;
static constexpr size_t O_A1T_H = 98816, O_A1T_L = 99072;
static constexpr size_t O_V1T_H = 99328, O_V1T_L = 99456;
static constexpr size_t O_G1T_H = 99584, O_G1T_L = 100096;  // ends 100608
static constexpr size_t O_WOT_H = 0, O_WOT_L = 8192;
// d_out layout (KB): gbf 0..8192 | HW2 8192 HA2 8704 HV2 9216 HG2 9472..10496
//   | up-weight planes 10496..12800 (dead before obf) | obf 8192..16384 (after scan)
static constexpr size_t D_W2T_H = 10496, D_W2T_L = 10752;
static constexpr size_t D_A2T_H = 11008, D_A2T_L = 11264;
static constexpr size_t D_V2T_H = 11520, D_V2T_L = 11648;
static constexpr size_t D_G2T_H = 11776, D_G2T_L = 12288;   // -> 12800

extern "C" void kernel_launch(void* const* d_in, const int* in_sizes, int n_in,
                              void* d_out, int out_size, void* d_ws, size_t ws_size,
                              hipStream_t stream) {
  const float* x      = (const float*)d_in[0];
  const float* vfirst = (const float*)d_in[1];
  const float* shift  = (const float*)d_in[2];
  const float* wkv0   = (const float*)d_in[3];
  const float* x_r = (const float*)d_in[4];
  const float* x_w = (const float*)d_in[5];
  const float* x_k = (const float*)d_in[6];
  const float* x_v = (const float*)d_in[7];
  const float* x_a = (const float*)d_in[8];
  const float* x_g = (const float*)d_in[9];
  const float* w0 = (const float*)d_in[10];
  const float* w1 = (const float*)d_in[11];
  const float* w2 = (const float*)d_in[12];
  const float* a0 = (const float*)d_in[13];
  const float* a1 = (const float*)d_in[14];
  const float* a2 = (const float*)d_in[15];
  const float* v0 = (const float*)d_in[16];
  const float* v1 = (const float*)d_in[17];
  const float* v2 = (const float*)d_in[18];
  const float* g1 = (const float*)d_in[19];
  const float* g2 = (const float*)d_in[20];
  const float* k_k = (const float*)d_in[21];
  const float* k_a = (const float*)d_in[22];
  const float* r_k = (const float*)d_in[23];
  const float* W_r = (const float*)d_in[24];
  const float* W_k = (const float*)d_in[25];
  const float* W_v = (const float*)d_in[26];
  const float* W_o = (const float*)d_in[27];
  const float* ln_w = (const float*)d_in[28];
  const float* ln_b = (const float*)d_in[29];

  char* ws = (char*)d_ws;
  auto F = [&](size_t kb) { return (float*)(ws + kb * KB); };
  auto U = [&](size_t kb) { return (unsigned short*)(ws + kb * KB); };
  auto D = [&](size_t kb) { return (unsigned short*)((char*)d_out + kb * KB); };
  float* outp = (float*)d_out;
  unsigned short* gbf = (unsigned short*)d_out;                       // 8 MiB
  unsigned short* obf = (unsigned short*)((char*)d_out + 8192 * KB);  // 8 MiB
  float* HW2 = (float*)((char*)d_out + 8192 * KB);                    // 512 KiB
  float* HA2 = (float*)((char*)d_out + 8704 * KB);                    // 512 KiB
  float* HV2 = (float*)((char*)d_out + 9216 * KB);                    // 256 KiB
  float* HG2 = (float*)((char*)d_out + 9472 * KB);                    // 1024 KiB

  // T1: transpose+split all 11 weights (downs into ws, ups into d_out tail).
  {
    TJobs TG{};
    int cum = 0, i = 0;
    auto addT = [&](const float* src, unsigned short* dh, unsigned short* dl,
                    int N, int K) {
      int ntn = (N + 63) / 64;
      cum += ((K + 63) / 64) * ntn;
      TG.j[i++] = TJob{src, dh, dl, N, K, ntn, cum};
    };
    addT(W_r, U(O_WRT_H), U(O_WRT_L), 2048, 2048);
    addT(W_k, U(O_WKT_H), U(O_WKT_L), 2048, 2048);
    addT(W_v, U(O_WVT_H), U(O_WVT_L), 2048, 2048);
    addT(w1, U(O_W1T_H), U(O_W1T_L), 64, 2048);
    addT(a1, U(O_A1T_H), U(O_A1T_L), 64, 2048);
    addT(v1, U(O_V1T_H), U(O_V1T_L), 32, 2048);
    addT(g1, U(O_G1T_H), U(O_G1T_L), 128, 2048);
    addT(w2, D(D_W2T_H), D(D_W2T_L), 2048, 64);
    addT(a2, D(D_A2T_H), D(D_A2T_L), 2048, 64);
    addT(v2, D(D_V2T_H), D(D_V2T_L), 2048, 32);
    addT(g2, D(D_G2T_H), D(D_G2T_L), 2048, 128);
    wtrans<<<dim3(cum), dim3(256), 0, stream>>>(TG);
  }

  // G1 (gemm_w256): r,k,v + 4 LoRA-downs with fused token-shift mixes.
  {
    GJobs G{};
    int cum = 0, i = 0;
    auto add = [&](size_t hkb, size_t lkb, float* Cp, const float* mixv, int N) {
      int ntn = (N + 255) / 256;
      cum += 16 * ntn;
      G.j[i++] = GJob{x, U(hkb), U(lkb), Cp, mixv, shift, nullptr,
                      N, 2048, ntn, 0, 2048, 0, 0, 0, cum};
    };
    add(O_WRT_H, O_WRT_L, F(O_R), x_r, 2048);
    add(O_WKT_H, O_WKT_L, F(O_K), x_k, 2048);
    add(O_WVT_H, O_WVT_L, F(O_V), x_v, 2048);
    add(O_W1T_H, O_W1T_L, HW2, x_w, 64);
    add(O_A1T_H, O_A1T_L, HA2, x_a, 64);
    add(O_V1T_H, O_V1T_L, HV2, x_v, 32);
    add(O_G1T_H, O_G1T_L, HG2, x_g, 128);
    gemm_w256<<<dim3(cum), dim3(256), 0, stream>>>(G);
  }

  // G2 (gemm_up, small-K): LoRA-up with fused activations/epilogues.
  {
    GJobs G{};
    int cum = 0, i = 0;
    auto add = [&](const float* A, size_t whkb, size_t wlkb, float* Cp,
                   const float* bias, int K, int aact, int epi) {
      cum += 16 * 8;
      G.j[i++] = GJob{A, D(whkb), D(wlkb), Cp, nullptr, nullptr, bias,
                      2048, K, 8, 0, K, 0, aact, epi, cum};
    };
    add(HW2, D_W2T_H, D_W2T_L, F(O_WDEC), w0, 64, 1, 2);
    add(HA2, D_A2T_H, D_A2T_L, F(O_AMAT), a0, 64, 0, 1);
    add(HV2, D_V2T_H, D_V2T_L, F(O_VMIX), v0, 32, 0, 1);
    add(HG2, D_G2T_H, D_G2T_L, (float*)gbf, nullptr, 128, 2, 3);
    gemm_up<<<dim3(cum), dim3(256), 0, stream>>>(G);
  }

  // prescan v2.
  prescan<<<dim3(16384), dim3(256), 0, stream>>>(F(O_K), F(O_V), F(O_AMAT), F(O_VMIX),
                                                 vfirst, k_k, k_a);

  // scan v10: 1024 blocks x 512 threads (8 segments x 2 v-halves, 96-step warmup).
  wkv_scan_v10<<<dim3(1024), dim3(512), 0, stream>>>(F(O_R), F(O_K), F(O_WDEC), F(O_AIN),
                                                     F(O_BIN), F(O_V), wkv0, obf);

  // post v2.
  post<<<dim3(16384), dim3(256), 0, stream>>>(obf, F(O_R), F(O_K), F(O_V),
                                              gbf, r_k, ln_w, ln_b, F(O_AFIN));

  // d_out consumed by post -> zero it for G3's split-K atomic accumulation.
  hipMemsetAsync(d_out, 0, (size_t)16384 * KB, stream);

  // T2: W_o transpose+split into dead r region.
  {
    TJobs TO{};
    TO.j[0] = TJob{W_o, U(O_WOT_H), U(O_WOT_L), 2048, 2048, 32, 1024};
    wtrans<<<dim3(1024), dim3(256), 0, stream>>>(TO);
  }

  // G3 (gemm_w256, split-K 4, atomic): out = afin @ W_o. Grid == last tile_end.
  {
    GJobs G{};
    G.j[0] = GJob{F(O_AFIN), U(O_WOT_H), U(O_WOT_L), outp, nullptr, nullptr, nullptr,
                  2048, 2048, 8, 0, 512, 1, 0, 0, 128};
    G.j[1] = GJob{F(O_AFIN), U(O_WOT_H), U(O_WOT_L), outp, nullptr, nullptr, nullptr,
                  2048, 2048, 8, 512, 1024, 1, 0, 0, 256};
    G.j[2] = GJob{F(O_AFIN), U(O_WOT_H), U(O_WOT_L), outp, nullptr, nullptr, nullptr,
                  2048, 2048, 8, 1024, 1536, 1, 0, 0, 384};
    G.j[3] = GJob{F(O_AFIN), U(O_WOT_H), U(O_WOT_L), outp, nullptr, nullptr, nullptr,
                  2048, 2048, 8, 1536, 2048, 1, 0, 0, 512};
    gemm_w256<<<dim3(512), dim3(256), 0, stream>>>(G);
  }

  (void)in_sizes; (void)n_in; (void)out_size; (void)ws_size;
}

// Round 22
// 696.577 us; speedup vs baseline: 2.2249x; 1.0347x over previous
//
#include <hip/hip_runtime.h>
#include <cstdint>
#include <cstddef>

// RWKV-7 Tmix forward, MI355X gfx950 — ROUND 26: scan v9 restored, WU 96->48.
// r25 isolated scan v10: 16 µs WORSE than v9 — segmentation crossed break-even
// (scan is VALU-throughput-bound at 16+ waves/CU: makespan tracks TOTAL work,
// and v10's warmup overhead is +29%). Restore v9 (4 seg x 4 vquad, 256 thr,
// proven 704 total) and trim warmup: WU=48 (carryover <= e^-24 conservative,
// ~1e-40 realistic since w <= e^-1.9/channel; WU=96 was bit-identical to the
// fp32 oracle). Scan work 1312 -> 1168 block-steps. GEMMs: proven (256,2)
// specialized kernels (G1 218 µs / 36.6% Mfma = 2-barrier structural ceiling).

#define DI __device__ __forceinline__
static constexpr int T_ = 1024, C_ = 2048, H_ = 32;

typedef __attribute__((ext_vector_type(8))) __bf16 bf16x8;
typedef __attribute__((ext_vector_type(4))) float f32x4;
typedef __attribute__((ext_vector_type(8))) unsigned short us8v;
typedef __attribute__((ext_vector_type(4))) unsigned short us4v;
typedef __attribute__((ext_vector_type(2))) unsigned short us2v;

DI float sig_(float z) { return 1.0f / (1.0f + expf(-z)); }

DI unsigned short f2bf(float f) {           // round-to-nearest-even f32 -> bf16
  union { float f; uint32_t u; } v; v.f = f;
  uint32_t u = v.u;
  return (unsigned short)((u + 0x7FFFu + ((u >> 16) & 1u)) >> 16);
}
DI float bf2f(unsigned short h) {
  union { uint32_t u; float f; } v; v.u = ((uint32_t)h) << 16;
  return v.f;
}

// DPP butterfly adds over 16 k-lanes (kq = lane&15).
DI float dpp_xor1_add(float x) {
  int r = __builtin_amdgcn_update_dpp(0, __float_as_int(x), 0xB1, 0xF, 0xF, true);
  return x + __int_as_float(r);
}
DI float dpp_xor2_add(float x) {
  int r = __builtin_amdgcn_update_dpp(0, __float_as_int(x), 0x4E, 0xF, 0xF, true);
  return x + __int_as_float(r);
}
DI float dpp_hm_add(float x) {
  int r = __builtin_amdgcn_update_dpp(0, __float_as_int(x), 0x141, 0xF, 0xF, true);
  return x + __int_as_float(r);
}
DI float dpp_mir_add(float x) {
  int r = __builtin_amdgcn_update_dpp(0, __float_as_int(x), 0x140, 0xF, 0xF, true);
  return x + __int_as_float(r);
}

// async global -> LDS DMA (dest = wave-uniform base + lane*size).
DI void gload16(const float* g, float* l) {
  __builtin_amdgcn_global_load_lds(
      (const __attribute__((address_space(1))) uint32_t*)g,
      (__attribute__((address_space(3))) uint32_t*)l, 16, 0, 0);
}
DI void gload16u(const unsigned short* g, unsigned short* l) {
  __builtin_amdgcn_global_load_lds(
      (const __attribute__((address_space(1))) uint32_t*)g,
      (__attribute__((address_space(3))) uint32_t*)l, 16, 0, 0);
}
DI void gload4(const float* g, float* l) {
  __builtin_amdgcn_global_load_lds(
      (const __attribute__((address_space(1))) uint32_t*)g,
      (__attribute__((address_space(3))) uint32_t*)l, 4, 0, 0);
}

// ---- weight transpose+split (generalized): src fp32 [K][N] -> hi/lo bf16 [N][K] ----
struct TJob { const float* src; unsigned short* dh; unsigned short* dl;
              int N, K, ntn, tile_end; };
struct TJobs { TJob j[12]; };

__global__ __launch_bounds__(256) void wtrans(TJobs P) {
  __shared__ float t[64][65];
  int bx = blockIdx.x, ji = 0;
  while (ji < 11 && bx >= P.j[ji].tile_end) ++ji;
  TJob J = P.j[ji];
  int tix = bx - (ji ? P.j[ji - 1].tile_end : 0);
  int kt = tix / J.ntn, nt = tix % J.ntn;
  int k0 = kt * 64, n0 = nt * 64;
  int tid = threadIdx.x;
  #pragma unroll
  for (int p = 0; p < 16; ++p) {
    int flat = p * 256 + tid;
    int r = flat >> 6, c = flat & 63;
    int n = n0 + c;
    t[r][c] = (n < J.N && k0 + r < J.K) ? J.src[(size_t)(k0 + r) * J.N + n] : 0.0f;
  }
  __syncthreads();
  #pragma unroll
  for (int p = 0; p < 8; ++p) {
    int flat = p * 256 + tid;
    int rr = flat >> 5, cc = (flat & 31) * 2;
    if (n0 + rr < J.N && k0 + cc < J.K) {
      float w0v = t[cc][rr], w1v = t[cc + 1][rr];
      unsigned short h0 = f2bf(w0v), h1 = f2bf(w1v);
      us2v oh, ol;
      oh.x = h0; oh.y = h1;
      ol.x = f2bf(w0v - bf2f(h0));
      ol.y = f2bf(w1v - bf2f(h1));
      size_t off = (size_t)(n0 + rr) * J.K + k0 + cc;
      *(us2v*)(J.dh + off) = oh;
      *(us2v*)(J.dl + off) = ol;
    }
  }
}

// ---------- split-bf16 MFMA GEMM, 128x256 tile (proven hot path, (256,2)) ----------
struct GJob {
  const float* A; const unsigned short* Wh; const unsigned short* Wl; float* C;
  const float* mixv; const float* shift; const float* bias;
  int N, K, ntn, kbeg, kend, atomicC, aact, epi, tile_end;
};
struct GJobs { GJob j[8]; };

__global__ __launch_bounds__(256, 2) void gemm_w256(GJobs P) {
  __shared__ unsigned short Ash[128][40];
  __shared__ unsigned short Asl[128][40];
  __shared__ unsigned short Bsh[256][32];
  __shared__ unsigned short Bsl[256][32];
  int bx = blockIdx.x, ji = 0;
  while (ji < 7 && bx >= P.j[ji].tile_end) ++ji;
  GJob J = P.j[ji];
  int tix = bx - (ji ? P.j[ji - 1].tile_end : 0);
  int mt = tix / J.ntn, nt = tix % J.ntn;
  int m0 = mt * 128, n0 = nt * 256;
  int tid = threadIdx.x;
  int lane = tid & 63, wid = tid >> 6;
  int wr = wid >> 1, wc = wid & 1;
  int l15 = lane & 15, lg = lane >> 4;
  f32x4 acc[4][8] = {};

  int sr = tid >> 3, skq = tid & 7;
  float ax[4][4], aq[4][4], amv[4];

  auto loadA = [&](int k0) {
    int kk = k0 + skq * 4;
    if (J.mixv) *(float4*)amv = *(const float4*)(J.mixv + kk);
    #pragma unroll
    for (int p = 0; p < 4; ++p) {
      int m = m0 + p * 32 + sr;
      const float* xp0 = J.A + (size_t)m * J.K + kk;
      *(float4*)ax[p] = *(const float4*)xp0;
      if (J.mixv) {
        const float* pp = ((m & (T_ - 1)) == 0)
            ? (J.shift + (size_t)(m >> 10) * C_ + kk)
            : (xp0 - C_);
        *(float4*)aq[p] = *(const float4*)pp;
      }
    }
  };
  auto writeA = [&]() {
    #pragma unroll
    for (int p = 0; p < 4; ++p) {
      us4v oh, ol;
      #pragma unroll
      for (int q = 0; q < 4; ++q) {
        float va = J.mixv ? (ax[p][q] + (aq[p][q] - ax[p][q]) * amv[q]) : ax[p][q];
        unsigned short hq = f2bf(va);
        oh[q] = hq;
        ol[q] = f2bf(va - bf2f(hq));
      }
      int r = p * 32 + sr;
      *(us4v*)&Ash[r][skq * 4] = oh;
      *(us4v*)&Asl[r][skq * 4] = ol;
    }
  };
  auto stageB = [&](int k0) {
    #pragma unroll
    for (int j = 0; j < 4; ++j) {
      int r0 = wid * 64 + j * 16;
      int rdst = r0 + (lane >> 2);
      int nrow = n0 + rdst;
      if (nrow >= J.N) nrow = J.N - 1;
      int ssrc = (lane & 3) ^ ((rdst >> 1) & 3);
      size_t gofs = (size_t)nrow * J.K + k0 + ssrc * 8;
      gload16u(J.Wh + gofs, &Bsh[r0][0]);
      gload16u(J.Wl + gofs, &Bsl[r0][0]);
    }
  };

  loadA(J.kbeg);
  stageB(J.kbeg);
  writeA();
  asm volatile("s_waitcnt vmcnt(0)" ::: "memory");
  __syncthreads();

  for (int k0 = J.kbeg; k0 < J.kend; k0 += 32) {
    bool more = (k0 + 32 < J.kend);
    if (more) loadA(k0 + 32);
    bf16x8 afh[4], afl[4];
    #pragma unroll
    for (int i = 0; i < 4; ++i) {
      int rr = wr * 64 + i * 16 + l15;
      afh[i] = __builtin_bit_cast(bf16x8, *(const us8v*)&Ash[rr][lg * 8]);
      afl[i] = __builtin_bit_cast(bf16x8, *(const us8v*)&Asl[rr][lg * 8]);
    }
    #pragma unroll
    for (int jn = 0; jn < 8; ++jn) {
      int rb = wc * 128 + jn * 16 + l15;
      int sl = (lg ^ ((rb >> 1) & 3)) * 8;
      bf16x8 bh = __builtin_bit_cast(bf16x8, *(const us8v*)&Bsh[rb][sl]);
      bf16x8 bl = __builtin_bit_cast(bf16x8, *(const us8v*)&Bsl[rb][sl]);
      #pragma unroll
      for (int i = 0; i < 4; ++i) {
        acc[i][jn] = __builtin_amdgcn_mfma_f32_16x16x32_bf16(afh[i], bh, acc[i][jn], 0, 0, 0);
        acc[i][jn] = __builtin_amdgcn_mfma_f32_16x16x32_bf16(afl[i], bh, acc[i][jn], 0, 0, 0);
        acc[i][jn] = __builtin_amdgcn_mfma_f32_16x16x32_bf16(afh[i], bl, acc[i][jn], 0, 0, 0);
      }
    }
    __syncthreads();
    if (more) { stageB(k0 + 32); writeA(); }
    asm volatile("s_waitcnt vmcnt(0)" ::: "memory");
    __syncthreads();
  }

  int orow0 = m0 + wr * 64 + 4 * lg;
  int ocol0 = n0 + wc * 128 + l15;
  #pragma unroll
  for (int i = 0; i < 4; ++i) {
    #pragma unroll
    for (int jn = 0; jn < 8; ++jn) {
      int col = ocol0 + jn * 16;
      if (col < J.N) {
        #pragma unroll
        for (int rr = 0; rr < 4; ++rr) {
          size_t idx = (size_t)(orow0 + i * 16 + rr) * J.N + col;
          float v = acc[i][jn][rr];
          if (J.atomicC) atomicAdd(&J.C[idx], v);
          else           J.C[idx] = v;
        }
      }
    }
  }
}

// ---------- gemm_up: same body + aact/epi/bias (G2 LoRA-up only, small-K) ----------
__global__ __launch_bounds__(256, 2) void gemm_up(GJobs P) {
  __shared__ unsigned short Ash[128][40];
  __shared__ unsigned short Asl[128][40];
  __shared__ unsigned short Bsh[256][32];
  __shared__ unsigned short Bsl[256][32];
  int bx = blockIdx.x, ji = 0;
  while (ji < 7 && bx >= P.j[ji].tile_end) ++ji;
  GJob J = P.j[ji];
  int tix = bx - (ji ? P.j[ji - 1].tile_end : 0);
  int mt = tix / J.ntn, nt = tix % J.ntn;
  int m0 = mt * 128, n0 = nt * 256;
  int tid = threadIdx.x;
  int lane = tid & 63, wid = tid >> 6;
  int wr = wid >> 1, wc = wid & 1;
  int l15 = lane & 15, lg = lane >> 4;
  f32x4 acc[4][8] = {};

  int sr = tid >> 3, skq = tid & 7;
  float ax[4][4];

  auto loadA = [&](int k0) {
    int kk = k0 + skq * 4;
    #pragma unroll
    for (int p = 0; p < 4; ++p) {
      int m = m0 + p * 32 + sr;
      *(float4*)ax[p] = *(const float4*)(J.A + (size_t)m * J.K + kk);
    }
  };
  auto writeA = [&]() {
    #pragma unroll
    for (int p = 0; p < 4; ++p) {
      us4v oh, ol;
      #pragma unroll
      for (int q = 0; q < 4; ++q) {
        float va = ax[p][q];
        if (J.aact == 1) va = tanhf(va);
        else if (J.aact == 2) va = sig_(va);
        unsigned short hq = f2bf(va);
        oh[q] = hq;
        ol[q] = f2bf(va - bf2f(hq));
      }
      int r = p * 32 + sr;
      *(us4v*)&Ash[r][skq * 4] = oh;
      *(us4v*)&Asl[r][skq * 4] = ol;
    }
  };
  auto stageB = [&](int k0) {
    #pragma unroll
    for (int j = 0; j < 4; ++j) {
      int r0 = wid * 64 + j * 16;
      int rdst = r0 + (lane >> 2);
      int nrow = n0 + rdst;
      if (nrow >= J.N) nrow = J.N - 1;
      int ssrc = (lane & 3) ^ ((rdst >> 1) & 3);
      size_t gofs = (size_t)nrow * J.K + k0 + ssrc * 8;
      gload16u(J.Wh + gofs, &Bsh[r0][0]);
      gload16u(J.Wl + gofs, &Bsl[r0][0]);
    }
  };

  loadA(J.kbeg);
  stageB(J.kbeg);
  writeA();
  asm volatile("s_waitcnt vmcnt(0)" ::: "memory");
  __syncthreads();

  for (int k0 = J.kbeg; k0 < J.kend; k0 += 32) {
    bool more = (k0 + 32 < J.kend);
    if (more) loadA(k0 + 32);
    bf16x8 afh[4], afl[4];
    #pragma unroll
    for (int i = 0; i < 4; ++i) {
      int rr = wr * 64 + i * 16 + l15;
      afh[i] = __builtin_bit_cast(bf16x8, *(const us8v*)&Ash[rr][lg * 8]);
      afl[i] = __builtin_bit_cast(bf16x8, *(const us8v*)&Asl[rr][lg * 8]);
    }
    #pragma unroll
    for (int jn = 0; jn < 8; ++jn) {
      int rb = wc * 128 + jn * 16 + l15;
      int sl = (lg ^ ((rb >> 1) & 3)) * 8;
      bf16x8 bh = __builtin_bit_cast(bf16x8, *(const us8v*)&Bsh[rb][sl]);
      bf16x8 bl = __builtin_bit_cast(bf16x8, *(const us8v*)&Bsl[rb][sl]);
      #pragma unroll
      for (int i = 0; i < 4; ++i) {
        acc[i][jn] = __builtin_amdgcn_mfma_f32_16x16x32_bf16(afh[i], bh, acc[i][jn], 0, 0, 0);
        acc[i][jn] = __builtin_amdgcn_mfma_f32_16x16x32_bf16(afl[i], bh, acc[i][jn], 0, 0, 0);
        acc[i][jn] = __builtin_amdgcn_mfma_f32_16x16x32_bf16(afh[i], bl, acc[i][jn], 0, 0, 0);
      }
    }
    __syncthreads();
    if (more) { stageB(k0 + 32); writeA(); }
    asm volatile("s_waitcnt vmcnt(0)" ::: "memory");
    __syncthreads();
  }

  int orow0 = m0 + wr * 64 + 4 * lg;
  int ocol0 = n0 + wc * 128 + l15;
  #pragma unroll
  for (int i = 0; i < 4; ++i) {
    #pragma unroll
    for (int jn = 0; jn < 8; ++jn) {
      int col = ocol0 + jn * 16;
      if (col < J.N) {
        #pragma unroll
        for (int rr = 0; rr < 4; ++rr) {
          size_t idx = (size_t)(orow0 + i * 16 + rr) * J.N + col;
          float v = acc[i][jn][rr];
          if (J.epi == 1) v = sig_(J.bias[col] + v);
          else if (J.epi == 2) v = 0.60653065971263342f * sig_(J.bias[col] + v);
          if (J.epi == 3) ((unsigned short*)J.C)[idx] = f2bf(v);
          else            J.C[idx] = v;
        }
      }
    }
  }
}

// ------- prescan v2: 16384 blocks x 256 thr (wave = head); shfl reductions -------
__global__ __launch_bounds__(256) void prescan(
    float* __restrict__ kio, float* __restrict__ vio,
    float* __restrict__ amat_ain, float* __restrict__ vmix_bin,
    const float* __restrict__ vfirst,
    const float* __restrict__ k_k, const float* __restrict__ k_a) {
  int gh = blockIdx.x * 4 + (threadIdx.x >> 6);
  int lane = threadIdx.x & 63;
  int h = gh & (H_ - 1);
  size_t base = (size_t)gh * 64 + lane;
  int cc = h * 64 + lane;
  float kv = kio[base];
  float kkv = kv * k_k[cc];
  float ss = kkv * kkv;
  ss += __shfl_xor(ss, 1);  ss += __shfl_xor(ss, 2);  ss += __shfl_xor(ss, 4);
  ss += __shfl_xor(ss, 8);  ss += __shfl_xor(ss, 16); ss += __shfl_xor(ss, 32);
  float nrm = fmaxf(sqrtf(ss), 1e-12f);
  float kkn = kkv / nrm;
  float av = amat_ain[base];
  float vmv = vmix_bin[base];
  float vv = vio[base];
  kio[base] = kv * (1.0f + (av - 1.0f) * k_a[cc]);
  vio[base] = vv + (vfirst[base] - vv) * vmv;
  amat_ain[base] = -kkn;
  vmix_bin[base] = kkn * av;
}

// ---- wkv scan v9 (WU=48): 4 time-segments x 4 vquad-waves; 1024 blocks x 256 thr ----
// chain 64 x seg 4 x vq 4; block covers 16 v-rows (wave wid owns 4: vr=wid*4+vl).
// Per-wave layout = v6 (vl = lane>>4, kq = lane&15, S[4]). seg s>0 warms up
// from zero over WU=48 steps (carryover <= e^-24 conservative; ~1e-40 with the
// measured w <= e^-1.9 channel decay — WU=96 was bit-identical to fp32 oracle).
static constexpr int CH = 8;
static constexpr int SEG = 256, WU = 48;

#define LOADSTEP(BUF, S_, Aa, Ww, Kk, Bb, Rr, Vt)                  \
  {                                                                \
    *(float4*)&Aa[0] = *(const float4*)&lds[BUF][3][S_][kb];       \
    *(float4*)&Ww[0] = *(const float4*)&lds[BUF][2][S_][kb];       \
    *(float4*)&Kk[0] = *(const float4*)&lds[BUF][1][S_][kb];       \
    *(float4*)&Bb[0] = *(const float4*)&lds[BUF][4][S_][kb];       \
    *(float4*)&Rr[0] = *(const float4*)&lds[BUF][0][S_][kb];       \
    Vt = vtl[BUF][S_][vr];                                         \
  }

#define COMPSTEP(Aa, Ww, Kk, Bb, Rr, Vt, TIDX)                              \
  {                                                                         \
    float p0 = S[0] * Aa[0], p1 = S[1] * Aa[1];                             \
    p0 = fmaf(S[2], Aa[2], p0);                                             \
    p1 = fmaf(S[3], Aa[3], p1);                                             \
    float sa = p0 + p1;                                                     \
    sa = dpp_xor1_add(sa);                                                  \
    sa = dpp_xor2_add(sa);                                                  \
    sa = dpp_hm_add(sa);                                                    \
    sa = dpp_mir_add(sa);                                                   \
    S[0] = fmaf(S[0], Ww[0], fmaf(Vt, Kk[0], sa * Bb[0]));                  \
    S[1] = fmaf(S[1], Ww[1], fmaf(Vt, Kk[1], sa * Bb[1]));                  \
    S[2] = fmaf(S[2], Ww[2], fmaf(Vt, Kk[2], sa * Bb[2]));                  \
    S[3] = fmaf(S[3], Ww[3], fmaf(Vt, Kk[3], sa * Bb[3]));                  \
    float y0 = S[0] * Rr[0], y1 = S[1] * Rr[1];                             \
    y0 = fmaf(S[2], Rr[2], y0);                                             \
    y1 = fmaf(S[3], Rr[3], y1);                                             \
    float y = y0 + y1;                                                      \
    y = dpp_xor1_add(y);                                                    \
    y = dpp_xor2_add(y);                                                    \
    y = dpp_hm_add(y);                                                      \
    y = dpp_mir_add(y);                                                     \
    if (kq == 0 && (TIDX) >= outfrom)                                       \
      obf[bh + (size_t)(TIDX)*2048 + v0 + vr] = f2bf(y);                    \
  }

__global__ __launch_bounds__(256) void wkv_scan_v9(
    const float* __restrict__ r, const float* __restrict__ k2,
    const float* __restrict__ w, const float* __restrict__ ain,
    const float* __restrict__ bin, const float* __restrict__ vp,
    const float* __restrict__ sInit, unsigned short* __restrict__ obf) {
  __shared__ float lds[2][5][CH][64];      // 20 KiB
  __shared__ float vtl[2][CH][16];         // 1 KiB
  int D = blockIdx.x;
  int chain = (D & 7) + 8 * (D >> 7);      // a chain's 16 blocks share D&7 -> one XCD
  int inner = (D >> 3) & 15;
  int seg = inner >> 2, vq = inner & 3;
  int b = chain >> 5, h = chain & 31;
  int v0 = vq * 16;
  int tid = threadIdx.x;
  int wid = tid >> 6, lane = tid & 63;
  int vl = lane >> 4, kq = lane & 15;
  int kb = kq * 4;
  int vr = wid * 4 + vl;                   // 0..15 within block
  size_t bh = (size_t)(b * T_) * 2048 + (size_t)h * 64;

  float S[4];
  if (seg == 0) {
    const float* sp = sInit + (((size_t)chain * 64 + v0 + vr) * 64) + kb;
    float4 s0 = *(const float4*)sp;
    S[0] = s0.x; S[1] = s0.y; S[2] = s0.z; S[3] = s0.w;
  } else {
    S[0] = S[1] = S[2] = S[3] = 0.0f;      // warmed up over WU steps
  }

  const float* arr[5] = {r, k2, w, ain, bin};

  // 10 main DMAs (array d>>1, t-half d&1) over 4 waves; vt by waves 0,1.
  auto stage = [&](int buf, int t0) {
    for (int d = wid; d < 10; d += 4) {
      int a = d >> 1, hf = d & 1;
      size_t gofs = bh + (size_t)(t0 + hf * 4 + (lane >> 4)) * 2048 + (lane & 15) * 4;
      gload16(arr[a] + gofs, &lds[buf][a][hf * 4][0]);
    }
    if (wid < 2) {                         // vt: 8 steps x 16 v = 2 x 64 floats
      size_t gofs = bh + (size_t)(t0 + wid * 4 + (lane >> 4)) * 2048 + v0 + (lane & 15);
      gload4(vp + gofs, &vtl[buf][wid * 4][0]);
    }
  };

  int tstart = seg ? (seg * SEG - WU) : 0;
  int nch = (seg ? (SEG + WU) : SEG) / CH; // 38 or 32
  int outfrom = seg * SEG;

  stage(0, tstart);
  asm volatile("s_waitcnt vmcnt(0)" ::: "memory");
  __syncthreads();

  float A0[4], W0[4], K0[4], B0[4], R0[4], vt0;
  float A1[4], W1[4], K1[4], B1[4], R1[4], vt1;

  for (int c = 0; c < nch; ++c) {
    int cur = c & 1;
    int t0 = tstart + c * CH;
    if (c + 1 < nch) stage(cur ^ 1, t0 + CH);
    LOADSTEP(cur, 0, A0, W0, K0, B0, R0, vt0);
    #pragma unroll 2
    for (int s = 0; s < CH; s += 2) {
      LOADSTEP(cur, s + 1, A1, W1, K1, B1, R1, vt1);
      COMPSTEP(A0, W0, K0, B0, R0, vt0, t0 + s);
      if (s + 2 < CH) LOADSTEP(cur, s + 2, A0, W0, K0, B0, R0, vt0);
      COMPSTEP(A1, W1, K1, B1, R1, vt1, t0 + s + 1);
    }
    asm volatile("s_waitcnt vmcnt(0)" ::: "memory");
    __syncthreads();
  }
}

// ------- post v2: 16384 blocks x 256 thr (wave = head); shfl reductions, 0 barriers ----
__global__ __launch_bounds__(256) void post(
    const unsigned short* __restrict__ obf, const float* __restrict__ r,
    const float* __restrict__ k2, const float* __restrict__ vp,
    const unsigned short* __restrict__ gbf, const float* __restrict__ r_k,
    const float* __restrict__ lnw, const float* __restrict__ lnb,
    float* __restrict__ afin) {
  int gh = blockIdx.x * 4 + (threadIdx.x >> 6);
  int lane = threadIdx.x & 63;
  int h = gh & 31;
  size_t base = (size_t)gh * 64 + lane;
  int cc = h * 64 + lane;
  float ov = bf2f(obf[base]);
  float pr = r[base] * k2[base] * r_k[cc];
  float so = ov, so2 = ov * ov, sd = pr;
  #pragma unroll
  for (int d = 1; d <= 32; d <<= 1) {
    so  += __shfl_xor(so, d);
    so2 += __shfl_xor(so2, d);
    sd  += __shfl_xor(sd, d);
  }
  float mu = so * (1.0f / 64.0f);
  float var = so2 * (1.0f / 64.0f) - mu * mu;
  float on = (ov - mu) * rsqrtf(var + 6.4e-4f) * lnw[cc] + lnb[cc];
  float val = (on + sd * vp[base]) * bf2f(gbf[base]);
  afin[base] = val;
}

// ---------------- host ----------------
static constexpr size_t KB = 1024;
static constexpr size_t O_R    = 0;
static constexpr size_t O_K    = 16384;
static constexpr size_t O_V    = 32768;
static constexpr size_t O_WDEC = 49152;
static constexpr size_t O_AMAT = 65536;
static constexpr size_t O_VMIX = 81920;
static constexpr size_t O_AIN  = O_AMAT;
static constexpr size_t O_BIN  = O_VMIX;
static constexpr size_t O_AFIN = O_VMIX;
static constexpr size_t O_WRT_H = 49152, O_WRT_L = 57344;
static constexpr size_t O_WKT_H = 65536, O_WKT_L = 73728;
static constexpr size_t O_WVT_H = 81920, O_WVT_L = 90112;   // ends 98304
static constexpr size_t O_W1T_H = 98304, O_W1T_L = 98560;
static constexpr size_t O_A1T_H = 98816, O_A1T_L = 99072;
static constexpr size_t O_V1T_H = 99328, O_V1T_L = 99456;
static constexpr size_t O_G1T_H = 99584, O_G1T_L = 100096;  // ends 100608
static constexpr size_t O_WOT_H = 0, O_WOT_L = 8192;
// d_out layout (KB): gbf 0..8192 | HW2 8192 HA2 8704 HV2 9216 HG2 9472..10496
//   | up-weight planes 10496..12800 (dead before obf) | obf 8192..16384 (after scan)
static constexpr size_t D_W2T_H = 10496, D_W2T_L = 10752;
static constexpr size_t D_A2T_H = 11008, D_A2T_L = 11264;
static constexpr size_t D_V2T_H = 11520, D_V2T_L = 11648;
static constexpr size_t D_G2T_H = 11776, D_G2T_L = 12288;   // -> 12800

extern "C" void kernel_launch(void* const* d_in, const int* in_sizes, int n_in,
                              void* d_out, int out_size, void* d_ws, size_t ws_size,
                              hipStream_t stream) {
  const float* x      = (const float*)d_in[0];
  const float* vfirst = (const float*)d_in[1];
  const float* shift  = (const float*)d_in[2];
  const float* wkv0   = (const float*)d_in[3];
  const float* x_r = (const float*)d_in[4];
  const float* x_w = (const float*)d_in[5];
  const float* x_k = (const float*)d_in[6];
  const float* x_v = (const float*)d_in[7];
  const float* x_a = (const float*)d_in[8];
  const float* x_g = (const float*)d_in[9];
  const float* w0 = (const float*)d_in[10];
  const float* w1 = (const float*)d_in[11];
  const float* w2 = (const float*)d_in[12];
  const float* a0 = (const float*)d_in[13];
  const float* a1 = (const float*)d_in[14];
  const float* a2 = (const float*)d_in[15];
  const float* v0 = (const float*)d_in[16];
  const float* v1 = (const float*)d_in[17];
  const float* v2 = (const float*)d_in[18];
  const float* g1 = (const float*)d_in[19];
  const float* g2 = (const float*)d_in[20];
  const float* k_k = (const float*)d_in[21];
  const float* k_a = (const float*)d_in[22];
  const float* r_k = (const float*)d_in[23];
  const float* W_r = (const float*)d_in[24];
  const float* W_k = (const float*)d_in[25];
  const float* W_v = (const float*)d_in[26];
  const float* W_o = (const float*)d_in[27];
  const float* ln_w = (const float*)d_in[28];
  const float* ln_b = (const float*)d_in[29];

  char* ws = (char*)d_ws;
  auto F = [&](size_t kb) { return (float*)(ws + kb * KB); };
  auto U = [&](size_t kb) { return (unsigned short*)(ws + kb * KB); };
  auto D = [&](size_t kb) { return (unsigned short*)((char*)d_out + kb * KB); };
  float* outp = (float*)d_out;
  unsigned short* gbf = (unsigned short*)d_out;                       // 8 MiB
  unsigned short* obf = (unsigned short*)((char*)d_out + 8192 * KB);  // 8 MiB
  float* HW2 = (float*)((char*)d_out + 8192 * KB);                    // 512 KiB
  float* HA2 = (float*)((char*)d_out + 8704 * KB);                    // 512 KiB
  float* HV2 = (float*)((char*)d_out + 9216 * KB);                    // 256 KiB
  float* HG2 = (float*)((char*)d_out + 9472 * KB);                    // 1024 KiB

  // T1: transpose+split all 11 weights (downs into ws, ups into d_out tail).
  {
    TJobs TG{};
    int cum = 0, i = 0;
    auto addT = [&](const float* src, unsigned short* dh, unsigned short* dl,
                    int N, int K) {
      int ntn = (N + 63) / 64;
      cum += ((K + 63) / 64) * ntn;
      TG.j[i++] = TJob{src, dh, dl, N, K, ntn, cum};
    };
    addT(W_r, U(O_WRT_H), U(O_WRT_L), 2048, 2048);
    addT(W_k, U(O_WKT_H), U(O_WKT_L), 2048, 2048);
    addT(W_v, U(O_WVT_H), U(O_WVT_L), 2048, 2048);
    addT(w1, U(O_W1T_H), U(O_W1T_L), 64, 2048);
    addT(a1, U(O_A1T_H), U(O_A1T_L), 64, 2048);
    addT(v1, U(O_V1T_H), U(O_V1T_L), 32, 2048);
    addT(g1, U(O_G1T_H), U(O_G1T_L), 128, 2048);
    addT(w2, D(D_W2T_H), D(D_W2T_L), 2048, 64);
    addT(a2, D(D_A2T_H), D(D_A2T_L), 2048, 64);
    addT(v2, D(D_V2T_H), D(D_V2T_L), 2048, 32);
    addT(g2, D(D_G2T_H), D(D_G2T_L), 2048, 128);
    wtrans<<<dim3(cum), dim3(256), 0, stream>>>(TG);
  }

  // G1 (gemm_w256): r,k,v + 4 LoRA-downs with fused token-shift mixes.
  {
    GJobs G{};
    int cum = 0, i = 0;
    auto add = [&](size_t hkb, size_t lkb, float* Cp, const float* mixv, int N) {
      int ntn = (N + 255) / 256;
      cum += 16 * ntn;
      G.j[i++] = GJob{x, U(hkb), U(lkb), Cp, mixv, shift, nullptr,
                      N, 2048, ntn, 0, 2048, 0, 0, 0, cum};
    };
    add(O_WRT_H, O_WRT_L, F(O_R), x_r, 2048);
    add(O_WKT_H, O_WKT_L, F(O_K), x_k, 2048);
    add(O_WVT_H, O_WVT_L, F(O_V), x_v, 2048);
    add(O_W1T_H, O_W1T_L, HW2, x_w, 64);
    add(O_A1T_H, O_A1T_L, HA2, x_a, 64);
    add(O_V1T_H, O_V1T_L, HV2, x_v, 32);
    add(O_G1T_H, O_G1T_L, HG2, x_g, 128);
    gemm_w256<<<dim3(cum), dim3(256), 0, stream>>>(G);
  }

  // G2 (gemm_up, small-K): LoRA-up with fused activations/epilogues.
  {
    GJobs G{};
    int cum = 0, i = 0;
    auto add = [&](const float* A, size_t whkb, size_t wlkb, float* Cp,
                   const float* bias, int K, int aact, int epi) {
      cum += 16 * 8;
      G.j[i++] = GJob{A, D(whkb), D(wlkb), Cp, nullptr, nullptr, bias,
                      2048, K, 8, 0, K, 0, aact, epi, cum};
    };
    add(HW2, D_W2T_H, D_W2T_L, F(O_WDEC), w0, 64, 1, 2);
    add(HA2, D_A2T_H, D_A2T_L, F(O_AMAT), a0, 64, 0, 1);
    add(HV2, D_V2T_H, D_V2T_L, F(O_VMIX), v0, 32, 0, 1);
    add(HG2, D_G2T_H, D_G2T_L, (float*)gbf, nullptr, 128, 2, 3);
    gemm_up<<<dim3(cum), dim3(256), 0, stream>>>(G);
  }

  // prescan v2.
  prescan<<<dim3(16384), dim3(256), 0, stream>>>(F(O_K), F(O_V), F(O_AMAT), F(O_VMIX),
                                                 vfirst, k_k, k_a);

  // scan v9 (WU=48): 1024 blocks x 256 threads (4 segments x 4 vquads).
  wkv_scan_v9<<<dim3(1024), dim3(256), 0, stream>>>(F(O_R), F(O_K), F(O_WDEC), F(O_AIN),
                                                    F(O_BIN), F(O_V), wkv0, obf);

  // post v2.
  post<<<dim3(16384), dim3(256), 0, stream>>>(obf, F(O_R), F(O_K), F(O_V),
                                              gbf, r_k, ln_w, ln_b, F(O_AFIN));

  // d_out consumed by post -> zero it for G3's split-K atomic accumulation.
  hipMemsetAsync(d_out, 0, (size_t)16384 * KB, stream);

  // T2: W_o transpose+split into dead r region.
  {
    TJobs TO{};
    TO.j[0] = TJob{W_o, U(O_WOT_H), U(O_WOT_L), 2048, 2048, 32, 1024};
    wtrans<<<dim3(1024), dim3(256), 0, stream>>>(TO);
  }

  // G3 (gemm_w256, split-K 4, atomic): out = afin @ W_o. Grid == last tile_end.
  {
    GJobs G{};
    G.j[0] = GJob{F(O_AFIN), U(O_WOT_H), U(O_WOT_L), outp, nullptr, nullptr, nullptr,
                  2048, 2048, 8, 0, 512, 1, 0, 0, 128};
    G.j[1] = GJob{F(O_AFIN), U(O_WOT_H), U(O_WOT_L), outp, nullptr, nullptr, nullptr,
                  2048, 2048, 8, 512, 1024, 1, 0, 0, 256};
    G.j[2] = GJob{F(O_AFIN), U(O_WOT_H), U(O_WOT_L), outp, nullptr, nullptr, nullptr,
                  2048, 2048, 8, 1024, 1536, 1, 0, 0, 384};
    G.j[3] = GJob{F(O_AFIN), U(O_WOT_H), U(O_WOT_L), outp, nullptr, nullptr, nullptr,
                  2048, 2048, 8, 1536, 2048, 1, 0, 0, 512};
    gemm_w256<<<dim3(512), dim3(256), 0, stream>>>(G);
  }

  (void)in_sizes; (void)n_in; (void)out_size; (void)ws_size;
}